// Round 4
// baseline (1106.564 us; speedup 1.0000x reference)
//
#include <hip/hip_runtime.h>

typedef __bf16 bf16;
typedef __attribute__((ext_vector_type(8))) __bf16 bf16x8;
typedef __attribute__((ext_vector_type(4))) float f32x4;

#define B_   4
#define T_   2048
#define C_   768
#define H_   8
#define HS_  96
#define M_   (B_ * T_)      /* 8192 */
#define QKN_ (3 * C_)       /* 2304 */

#define NEG_BIG (-1e30f)

// ---------------------------------------------------------------------------
// Transpose + convert: W[R][Cn] (fp32) -> Wt[Cn][R] (bf16)
// ---------------------------------------------------------------------------
__global__ void transpose_kernel(const float* __restrict__ W, bf16* __restrict__ Wt,
                                 int R, int Cn) {
    __shared__ bf16 tile[32][33];
    int tx = threadIdx.x, ty = threadIdx.y;
    int x  = blockIdx.x * 32 + tx;        // column in W
    int y0 = blockIdx.y * 32;             // row base in W
#pragma unroll
    for (int j = 0; j < 32; j += 8)
        tile[ty + j][tx] = (bf16)W[(size_t)(y0 + ty + j) * Cn + x];
    __syncthreads();
    int y2 = blockIdx.x * 32;             // row base in Wt (= col in W)
    int x2 = y0 + tx;                     // col in Wt (= row in W)
#pragma unroll
    for (int j = 0; j < 32; j += 8)
        Wt[(size_t)(y2 + ty + j) * R + x2] = tile[tx][ty + j];
}

// ---------------------------------------------------------------------------
// Sentinel fill (fp32 now): absmax ~12345 next round => ws too small.
// ---------------------------------------------------------------------------
__global__ void sentinel_kernel(float* __restrict__ out, int n) {
    int i = blockIdx.x * 256 + threadIdx.x;
    if (i < n) out[i] = 12345.0f;
}

// ---------------------------------------------------------------------------
// A-operand staging helpers: load 8 k-elements as bf16x8, converting if fp32.
// ---------------------------------------------------------------------------
__device__ __forceinline__ bf16x8 load8(const bf16* p) {
    return *(const bf16x8*)p;
}
__device__ __forceinline__ bf16x8 load8(const float* p) {
    f32x4 v0 = *(const f32x4*)p;
    f32x4 v1 = *(const f32x4*)(p + 4);
    bf16x8 o;
#pragma unroll
    for (int i = 0; i < 4; ++i) { o[i] = (bf16)v0[i]; o[4 + i] = (bf16)v1[i]; }
    return o;
}

// Output store helpers (bf16 intermediate vs fp32 final).
__device__ __forceinline__ void store1(bf16* p, float v)  { *p = (bf16)v; }
__device__ __forceinline__ void store1(float* p, float v) { *p = v; }

// ---------------------------------------------------------------------------
// C[M][N] = A[M][K] @ Bt[N][K]^T + bias[N]   (A fp32-or-bf16, Bt bf16,
// bias fp32, C bf16-or-fp32, fp32 accum). 128x128 tile, BK=64, 256 threads
// (4 waves, each 64x64 via 4x4 16x16x32 MFMA tiles).
// ---------------------------------------------------------------------------
template <typename AT, typename CT>
__global__ __launch_bounds__(256) void gemm_bt(const AT* __restrict__ A,
                                               const bf16* __restrict__ Bt,
                                               const float* __restrict__ bias,
                                               CT* __restrict__ Cmat,
                                               int M, int N, int K) {
    __shared__ bf16 lda[128 * 72];   // padded: 144B row stride, breaks pow2 conflicts
    __shared__ bf16 ldb[128 * 72];
    int tid  = threadIdx.x;
    int w    = tid >> 6;
    int lane = tid & 63;
    int col  = lane & 15, quad = lane >> 4;
    int wr   = w >> 1, wc = w & 1;
    int m0   = blockIdx.y * 128, n0 = blockIdx.x * 128;

    const f32x4 zero = {0.f, 0.f, 0.f, 0.f};
    f32x4 acc[4][4];
#pragma unroll
    for (int mr = 0; mr < 4; ++mr)
#pragma unroll
        for (int nc = 0; nc < 4; ++nc) acc[mr][nc] = zero;

    for (int k0 = 0; k0 < K; k0 += 64) {
#pragma unroll
        for (int i = 0; i < 4; ++i) {
            int chunk = i * 256 + tid;      // 1024 chunks of 8 elements
            int r = chunk >> 3, cc = chunk & 7;
            *(bf16x8*)&lda[r * 72 + cc * 8] = load8(&A[(size_t)(m0 + r) * K + k0 + cc * 8]);
            *(bf16x8*)&ldb[r * 72 + cc * 8] = load8(&Bt[(size_t)(n0 + r) * K + k0 + cc * 8]);
        }
        __syncthreads();
#pragma unroll
        for (int ks = 0; ks < 2; ++ks) {
            bf16x8 af[4], bfr[4];
#pragma unroll
            for (int t = 0; t < 4; ++t) {
                af[t]  = *(const bf16x8*)&lda[(wr * 64 + t * 16 + col) * 72 + ks * 32 + quad * 8];
                bfr[t] = *(const bf16x8*)&ldb[(wc * 64 + t * 16 + col) * 72 + ks * 32 + quad * 8];
            }
#pragma unroll
            for (int mr = 0; mr < 4; ++mr)
#pragma unroll
                for (int nc = 0; nc < 4; ++nc)
                    acc[mr][nc] = __builtin_amdgcn_mfma_f32_16x16x32_bf16(
                        af[mr], bfr[nc], acc[mr][nc], 0, 0, 0);
        }
        __syncthreads();
    }

#pragma unroll
    for (int nc = 0; nc < 4; ++nc) {
        int n = n0 + wc * 64 + nc * 16 + col;
        float bv = bias[n];
#pragma unroll
        for (int mr = 0; mr < 4; ++mr) {
#pragma unroll
            for (int r = 0; r < 4; ++r) {
                int row = m0 + wr * 64 + mr * 16 + quad * 4 + r;
                store1(&Cmat[(size_t)row * N + n], acc[mr][nc][r] + bv);
            }
        }
    }
}

// ---------------------------------------------------------------------------
// Flash attention (causal), ONE BATCH. 1 wave per (h, 16 Q-rows).
// qkv is [T][3C] bf16 for this batch; y is [T][C] bf16 for this batch.
// ---------------------------------------------------------------------------
__global__ __launch_bounds__(64) void attn_kernel(const bf16* __restrict__ qkv,
                                                  bf16* __restrict__ y) {
    __shared__ bf16 ldsV[32 * 96];   // [j][n] row-major
    __shared__ bf16 ldsP[16 * 32];   // [m][j]
    int bid  = blockIdx.x;
    int qt   = bid & 127;
    int h    = bid >> 7;             // 0..7
    int lane = threadIdx.x;
    int col  = lane & 15, quad = lane >> 4;
    int qbase = qt * 16;

    const float scale = 0.10206207261596577f;   // 1/sqrt(96)

    // Preload Q fragments (A-layout: m=col, k=quad*8+j, contiguous in k)
    bf16x8 qf[3];
    {
        const bf16* qp = qkv + (size_t)(qbase + col) * QKN_ + h * HS_ + quad * 8;
#pragma unroll
        for (int c = 0; c < 3; ++c) qf[c] = *(const bf16x8*)(qp + c * 32);
    }

    const f32x4 zero = {0.f, 0.f, 0.f, 0.f};
    f32x4 o[6];
#pragma unroll
    for (int n2 = 0; n2 < 6; ++n2) o[n2] = zero;
    float mrow[4], lrow[4];
#pragma unroll
    for (int r = 0; r < 4; ++r) { mrow[r] = NEG_BIG; lrow[r] = 0.f; }

    int njt = ((qbase + 15) >> 5) + 1;
    for (int jt = 0; jt < njt; ++jt) {
        int jb = jt << 5;
        __syncthreads();
        // Stage V tile [32][96]
        {
            const bf16* vbase = qkv + (size_t)jb * QKN_ + 2 * C_ + h * HS_;
#pragma unroll
            for (int it = 0; it < 6; ++it) {
                int chunk = it * 64 + lane;           // 384 chunks of 8 bf16
                int j = chunk / 12, nc8 = chunk % 12;
                *(bf16x8*)&ldsV[j * 96 + nc8 * 8] =
                    *(const bf16x8*)(vbase + (size_t)j * QKN_ + nc8 * 8);
            }
        }
        // S = Q K^T (two 16-col blocks), scale + causal mask
        f32x4 sblk[2];
#pragma unroll
        for (int nb = 0; nb < 2; ++nb) {
            int j16 = jb + nb * 16;
            const bf16* kp = qkv + (size_t)(j16 + col) * QKN_ + C_ + h * HS_ + quad * 8;
            f32x4 s = zero;
#pragma unroll
            for (int c = 0; c < 3; ++c) {
                bf16x8 kf = *(const bf16x8*)(kp + c * 32);
                s = __builtin_amdgcn_mfma_f32_16x16x32_bf16(qf[c], kf, s, 0, 0, 0);
            }
#pragma unroll
            for (int r = 0; r < 4; ++r) {
                int ig = qbase + quad * 4 + r;
                int jg = j16 + col;
                sblk[nb][r] = (jg <= ig) ? s[r] * scale : NEG_BIG;
            }
        }
        // Online softmax (rows live in 16-lane groups sharing a quad)
        float alpha[4];
#pragma unroll
        for (int r = 0; r < 4; ++r) {
            float mx = fmaxf(sblk[0][r], sblk[1][r]);
#pragma unroll
            for (int off = 1; off < 16; off <<= 1) mx = fmaxf(mx, __shfl_xor(mx, off, 64));
            float mnew = fmaxf(mrow[r], mx);
            float p0 = __expf(sblk[0][r] - mnew);
            float p1 = __expf(sblk[1][r] - mnew);
            sblk[0][r] = p0; sblk[1][r] = p1;
            float sum = p0 + p1;
#pragma unroll
            for (int off = 1; off < 16; off <<= 1) sum += __shfl_xor(sum, off, 64);
            alpha[r] = __expf(mrow[r] - mnew);
            lrow[r]  = lrow[r] * alpha[r] + sum;
            mrow[r]  = mnew;
        }
        // P -> LDS (bf16), rescale O
#pragma unroll
        for (int nb = 0; nb < 2; ++nb)
#pragma unroll
            for (int r = 0; r < 4; ++r)
                ldsP[(quad * 4 + r) * 32 + nb * 16 + col] = (bf16)sblk[nb][r];
#pragma unroll
        for (int n2 = 0; n2 < 6; ++n2)
#pragma unroll
            for (int r = 0; r < 4; ++r) o[n2][r] *= alpha[r];
        __syncthreads();
        // O += P @ V
        bf16x8 pf = *(const bf16x8*)&ldsP[col * 32 + quad * 8];
#pragma unroll
        for (int n2 = 0; n2 < 6; ++n2) {
            bf16x8 vf;
#pragma unroll
            for (int jj = 0; jj < 8; ++jj)
                vf[jj] = ldsV[(quad * 8 + jj) * 96 + n2 * 16 + col];
            o[n2] = __builtin_amdgcn_mfma_f32_16x16x32_bf16(pf, vf, o[n2], 0, 0, 0);
        }
    }
    // Epilogue: divide by (l + 1e-9), store y
    float linv[4];
#pragma unroll
    for (int r = 0; r < 4; ++r) linv[r] = 1.0f / (lrow[r] + 1e-9f);
#pragma unroll
    for (int n2 = 0; n2 < 6; ++n2)
#pragma unroll
        for (int r = 0; r < 4; ++r)
            y[(size_t)(qbase + quad * 4 + r) * C_ + h * HS_ + n2 * 16 + col] =
                (bf16)(o[n2][r] * linv[r]);
}

// ---------------------------------------------------------------------------
extern "C" void kernel_launch(void* const* d_in, const int* in_sizes, int n_in,
                              void* d_out, int out_size, void* d_ws, size_t ws_size,
                              hipStream_t stream) {
    (void)in_sizes; (void)n_in;
    // Inputs fp32 (round-2 NaN proof). Output fp32 (reference returns float32;
    // round-3's 4.83 absmax matched bf16-pairs-in-fp32-buffer exactly).
    const float* x      = (const float*)d_in[0];
    const float* W_attn = (const float*)d_in[1];
    const float* b_attn = (const float*)d_in[2];
    const float* W_proj = (const float*)d_in[3];
    const float* b_proj = (const float*)d_in[4];
    float* out = (float*)d_out;

    // Per-batch workspace layout (16.5 MB):
    //   Wt_attn [2304][768] | Wt_proj [768][768] | qkv_b [2048][2304] | yb_b [2048][768]
    size_t off_wta = 0;
    size_t off_wtp = off_wta + (size_t)QKN_ * C_;
    size_t off_qkv = off_wtp + (size_t)C_ * C_;
    size_t off_yb  = off_qkv + (size_t)T_ * QKN_;
    size_t need    = (off_yb + (size_t)T_ * C_) * sizeof(bf16);

    if (ws_size < need) {
        sentinel_kernel<<<(out_size + 255) / 256, 256, 0, stream>>>(out, out_size);
        return;
    }

    bf16* Wt_attn = (bf16*)d_ws + off_wta;
    bf16* Wt_proj = (bf16*)d_ws + off_wtp;
    bf16* qkv_b   = (bf16*)d_ws + off_qkv;
    bf16* yb_b    = (bf16*)d_ws + off_yb;

    transpose_kernel<<<dim3(QKN_ / 32, C_ / 32), dim3(32, 8), 0, stream>>>(W_attn, Wt_attn, C_, QKN_);
    transpose_kernel<<<dim3(C_ / 32, C_ / 32), dim3(32, 8), 0, stream>>>(W_proj, Wt_proj, C_, C_);

    for (int b = 0; b < B_; ++b) {
        const float* xb = x + (size_t)b * T_ * C_;
        float* outb     = out + (size_t)b * T_ * C_;
        gemm_bt<float, bf16><<<dim3(QKN_ / 128, T_ / 128), 256, 0, stream>>>(
            xb, Wt_attn, b_attn, qkv_b, T_, QKN_, C_);
        attn_kernel<<<dim3(H_ * (T_ / 16)), 64, 0, stream>>>(qkv_b, yb_b);
        gemm_bt<bf16, float><<<dim3(C_ / 128, T_ / 128), 256, 0, stream>>>(
            yb_b, Wt_proj, b_proj, outb, T_, C_, C_);
    }
}

// Round 5
// 286.895 us; speedup vs baseline: 3.8570x; 3.8570x over previous
//
#include <hip/hip_runtime.h>

typedef __bf16 bf16;
typedef __attribute__((ext_vector_type(8))) __bf16 bf16x8;
typedef __attribute__((ext_vector_type(4))) float f32x4;

#define B_   4
#define T_   2048
#define C_   768
#define H_   8
#define HS_  96
#define M_   (B_ * T_)      /* 8192 */
#define QKN_ (3 * C_)       /* 2304 */

#define NEG_BIG (-1e30f)

// LDS strides (elements) chosen so b128 fragment reads are <=2-way conflicts
#define KSTR 104   /* 64x(96) K tile rows, padded 96->104 */
#define VSTR 72    /* 96x(64) Vt tile rows, padded 64->72 */
#define PSTR 72    /* 32x(64) P tile rows, padded 64->72 */

// ---------------------------------------------------------------------------
// Transpose + convert: W[R][Cn] (fp32) -> Wt[Cn][R] (bf16)
// ---------------------------------------------------------------------------
__global__ void transpose_kernel(const float* __restrict__ W, bf16* __restrict__ Wt,
                                 int R, int Cn) {
    __shared__ bf16 tile[32][33];
    int tx = threadIdx.x, ty = threadIdx.y;
    int x  = blockIdx.x * 32 + tx;
    int y0 = blockIdx.y * 32;
#pragma unroll
    for (int j = 0; j < 32; j += 8)
        tile[ty + j][tx] = (bf16)W[(size_t)(y0 + ty + j) * Cn + x];
    __syncthreads();
    int y2 = blockIdx.x * 32;
    int x2 = y0 + tx;
#pragma unroll
    for (int j = 0; j < 32; j += 8)
        Wt[(size_t)(y2 + ty + j) * R + x2] = tile[tx][ty + j];
}

// ---------------------------------------------------------------------------
// V-part transpose: qkv[b][t][2C + c] -> Vt[b][c][t]   (c in [0,768))
// ---------------------------------------------------------------------------
__global__ void v_transpose(const bf16* __restrict__ qkv, bf16* __restrict__ Vt) {
    __shared__ bf16 tile[32][33];
    int b = blockIdx.z;
    const bf16* src = qkv + (size_t)b * T_ * QKN_ + 2 * C_;
    bf16* dst = Vt + (size_t)b * C_ * T_;
    int tx = threadIdx.x, ty = threadIdx.y;
    int cc = blockIdx.x * 32;     // V-col base
    int tt = blockIdx.y * 32;     // t base
#pragma unroll
    for (int j = 0; j < 32; j += 8)
        tile[ty + j][tx] = src[(size_t)(tt + ty + j) * QKN_ + cc + tx];
    __syncthreads();
#pragma unroll
    for (int j = 0; j < 32; j += 8)
        dst[(size_t)(cc + ty + j) * T_ + tt + tx] = tile[tx][ty + j];
}

// ---------------------------------------------------------------------------
__global__ void sentinel_kernel(float* __restrict__ out, int n) {
    int i = blockIdx.x * 256 + threadIdx.x;
    if (i < n) out[i] = 12345.0f;
}

// ---------------------------------------------------------------------------
__device__ __forceinline__ bf16x8 load8(const bf16* p) { return *(const bf16x8*)p; }
__device__ __forceinline__ bf16x8 load8(const float* p) {
    f32x4 v0 = *(const f32x4*)p;
    f32x4 v1 = *(const f32x4*)(p + 4);
    bf16x8 o;
#pragma unroll
    for (int i = 0; i < 4; ++i) { o[i] = (bf16)v0[i]; o[4 + i] = (bf16)v1[i]; }
    return o;
}
__device__ __forceinline__ void store1(bf16* p, float v)  { *p = (bf16)v; }
__device__ __forceinline__ void store1(float* p, float v) { *p = v; }

// ---------------------------------------------------------------------------
// C[M][N] = A[M][K] @ Bt[N][K]^T + bias[N]
// ---------------------------------------------------------------------------
template <typename AT, typename CT>
__global__ __launch_bounds__(256) void gemm_bt(const AT* __restrict__ A,
                                               const bf16* __restrict__ Bt,
                                               const float* __restrict__ bias,
                                               CT* __restrict__ Cmat,
                                               int M, int N, int K) {
    __shared__ bf16 lda[128 * 72];
    __shared__ bf16 ldb[128 * 72];
    int tid  = threadIdx.x;
    int w    = tid >> 6;
    int lane = tid & 63;
    int col  = lane & 15, quad = lane >> 4;
    int wr   = w >> 1, wc = w & 1;
    int m0   = blockIdx.y * 128, n0 = blockIdx.x * 128;

    const f32x4 zero = {0.f, 0.f, 0.f, 0.f};
    f32x4 acc[4][4];
#pragma unroll
    for (int mr = 0; mr < 4; ++mr)
#pragma unroll
        for (int nc = 0; nc < 4; ++nc) acc[mr][nc] = zero;

    for (int k0 = 0; k0 < K; k0 += 64) {
#pragma unroll
        for (int i = 0; i < 4; ++i) {
            int chunk = i * 256 + tid;
            int r = chunk >> 3, cc = chunk & 7;
            *(bf16x8*)&lda[r * 72 + cc * 8] = load8(&A[(size_t)(m0 + r) * K + k0 + cc * 8]);
            *(bf16x8*)&ldb[r * 72 + cc * 8] = load8(&Bt[(size_t)(n0 + r) * K + k0 + cc * 8]);
        }
        __syncthreads();
#pragma unroll
        for (int ks = 0; ks < 2; ++ks) {
            bf16x8 af[4], bfr[4];
#pragma unroll
            for (int t = 0; t < 4; ++t) {
                af[t]  = *(const bf16x8*)&lda[(wr * 64 + t * 16 + col) * 72 + ks * 32 + quad * 8];
                bfr[t] = *(const bf16x8*)&ldb[(wc * 64 + t * 16 + col) * 72 + ks * 32 + quad * 8];
            }
#pragma unroll
            for (int mr = 0; mr < 4; ++mr)
#pragma unroll
                for (int nc = 0; nc < 4; ++nc)
                    acc[mr][nc] = __builtin_amdgcn_mfma_f32_16x16x32_bf16(
                        af[mr], bfr[nc], acc[mr][nc], 0, 0, 0);
        }
        __syncthreads();
    }

#pragma unroll
    for (int nc = 0; nc < 4; ++nc) {
        int n = n0 + wc * 64 + nc * 16 + col;
        float bv = bias[n];
#pragma unroll
        for (int mr = 0; mr < 4; ++mr) {
#pragma unroll
            for (int r = 0; r < 4; ++r) {
                int row = m0 + wr * 64 + mr * 16 + quad * 4 + r;
                store1(&Cmat[(size_t)row * N + n], acc[mr][nc][r] + bv);
            }
        }
    }
}

// ---------------------------------------------------------------------------
// Fused causal flash attention.
// Grid: (8 qt-pairs, H, B). Block: 256 thr (4 waves). Each block processes two
// 128-row Q-tiles (qt and 15-qt -> uniform 34 j-tiles). Wave owns 32 Q-rows.
// j-tile = 64: K (64x96) and Vt (96x64) staged in padded LDS, shared by waves.
// ---------------------------------------------------------------------------
__global__ __launch_bounds__(256) void attn_kernel(const bf16* __restrict__ qkv,
                                                   const bf16* __restrict__ Vt,
                                                   bf16* __restrict__ y) {
    __shared__ bf16 ldsK[64 * KSTR];
    __shared__ bf16 ldsV[96 * VSTR];
    __shared__ bf16 ldsP[4 * 32 * PSTR];
    const int tid  = threadIdx.x;
    const int w    = tid >> 6, lane = tid & 63;
    const int col  = lane & 15, quad = lane >> 4;
    const int h = blockIdx.y, b = blockIdx.z;
    const float scale = 0.10206207261596577f;   // 1/sqrt(96)
    const f32x4 zero = {0.f, 0.f, 0.f, 0.f};

    const bf16* qkvb = qkv + (size_t)b * T_ * QKN_;
    const bf16* Vtbh = Vt + (size_t)(b * H_ + h) * HS_ * T_;
    bf16* yb  = y + (size_t)b * T_ * C_;
    bf16* myP = &ldsP[w * 32 * PSTR];

    for (int half = 0; half < 2; ++half) {
        int qt    = half ? (15 - (int)blockIdx.x) : (int)blockIdx.x;
        int qbase = qt * 128;
        int rbase = qbase + w * 32;

        // Q fragments (A-layout, direct from global; contiguous in k)
        bf16x8 qf[2][3];
#pragma unroll
        for (int m = 0; m < 2; ++m)
#pragma unroll
            for (int c = 0; c < 3; ++c)
                qf[m][c] = *(const bf16x8*)&qkvb[(size_t)(rbase + m * 16 + col) * QKN_
                                                 + h * HS_ + c * 32 + quad * 8];

        f32x4 o[2][6];
        float mrow[2][4], lrow[2][4];
#pragma unroll
        for (int m = 0; m < 2; ++m) {
#pragma unroll
            for (int n2 = 0; n2 < 6; ++n2) o[m][n2] = zero;
#pragma unroll
            for (int r = 0; r < 4; ++r) { mrow[m][r] = NEG_BIG; lrow[m][r] = 0.f; }
        }

        int njt = 2 * qt + 2;
        for (int jt = 0; jt < njt; ++jt) {
            int jb = jt * 64;
            __syncthreads();   // all waves done reading previous K/V
            // Stage K tile [64][96] and Vt tile [96][64]
#pragma unroll
            for (int i = 0; i < 3; ++i) {
                int chunk = i * 256 + tid;           // 768 chunks of 8 elems each
                int r  = chunk / 12, cc = chunk - r * 12;
                *(bf16x8*)&ldsK[r * KSTR + cc * 8] =
                    *(const bf16x8*)&qkvb[(size_t)(jb + r) * QKN_ + C_ + h * HS_ + cc * 8];
                int r2 = chunk >> 3, c2 = chunk & 7;
                *(bf16x8*)&ldsV[r2 * VSTR + c2 * 8] =
                    *(const bf16x8*)&Vtbh[(size_t)r2 * T_ + jb + c2 * 8];
            }
            __syncthreads();

            // K fragments (shared across both m-blocks)
            bf16x8 kf[4][3];
#pragma unroll
            for (int nb = 0; nb < 4; ++nb)
#pragma unroll
                for (int c = 0; c < 3; ++c)
                    kf[nb][c] = *(const bf16x8*)&ldsK[(nb * 16 + col) * KSTR + c * 32 + quad * 8];

            bool skip[2];
#pragma unroll
            for (int m = 0; m < 2; ++m) {
                int bm = rbase + m * 16;
                skip[m] = (jb > bm + 15);            // tile fully above diagonal
                if (skip[m]) continue;
                f32x4 sblk[4];
#pragma unroll
                for (int nb = 0; nb < 4; ++nb) sblk[nb] = zero;
#pragma unroll
                for (int c = 0; c < 3; ++c)
#pragma unroll
                    for (int nb = 0; nb < 4; ++nb)
                        sblk[nb] = __builtin_amdgcn_mfma_f32_16x16x32_bf16(
                            qf[m][c], kf[nb][c], sblk[nb], 0, 0, 0);
                if (jb + 63 > bm) {                  // diagonal tile: mask
#pragma unroll
                    for (int nb = 0; nb < 4; ++nb)
#pragma unroll
                        for (int r = 0; r < 4; ++r) {
                            int ig = bm + quad * 4 + r;
                            int jg = jb + nb * 16 + col;
                            sblk[nb][r] = (jg <= ig) ? sblk[nb][r] * scale : NEG_BIG;
                        }
                } else {
#pragma unroll
                    for (int nb = 0; nb < 4; ++nb)
#pragma unroll
                        for (int r = 0; r < 4; ++r) sblk[nb][r] *= scale;
                }
                // online softmax (rows live across 16-lane groups)
                float alpha[4];
#pragma unroll
                for (int r = 0; r < 4; ++r) {
                    float mx = fmaxf(fmaxf(sblk[0][r], sblk[1][r]),
                                     fmaxf(sblk[2][r], sblk[3][r]));
#pragma unroll
                    for (int off = 1; off < 16; off <<= 1) mx = fmaxf(mx, __shfl_xor(mx, off, 64));
                    float mnew = fmaxf(mrow[m][r], mx);
                    float sum = 0.f;
#pragma unroll
                    for (int nb = 0; nb < 4; ++nb) {
                        float p = __expf(sblk[nb][r] - mnew);
                        sblk[nb][r] = p;
                        sum += p;
                    }
#pragma unroll
                    for (int off = 1; off < 16; off <<= 1) sum += __shfl_xor(sum, off, 64);
                    alpha[r] = __expf(mrow[m][r] - mnew);
                    lrow[m][r] = lrow[m][r] * alpha[r] + sum;
                    mrow[m][r] = mnew;
                }
                // P -> per-wave LDS (no barrier needed), rescale O
#pragma unroll
                for (int nb = 0; nb < 4; ++nb)
#pragma unroll
                    for (int r = 0; r < 4; ++r)
                        myP[(m * 16 + quad * 4 + r) * PSTR + nb * 16 + col] = (bf16)sblk[nb][r];
#pragma unroll
                for (int n2 = 0; n2 < 6; ++n2)
#pragma unroll
                    for (int r = 0; r < 4; ++r) o[m][n2][r] *= alpha[r];
            }

            // V fragments (shared across both m-blocks)
            bf16x8 vf[6][2];
#pragma unroll
            for (int n2 = 0; n2 < 6; ++n2)
#pragma unroll
                for (int c = 0; c < 2; ++c)
                    vf[n2][c] = *(const bf16x8*)&ldsV[(n2 * 16 + col) * VSTR + c * 32 + quad * 8];
#pragma unroll
            for (int m = 0; m < 2; ++m) {
                if (skip[m]) continue;
                bf16x8 pa0 = *(const bf16x8*)&myP[(m * 16 + col) * PSTR + quad * 8];
                bf16x8 pa1 = *(const bf16x8*)&myP[(m * 16 + col) * PSTR + 32 + quad * 8];
#pragma unroll
                for (int n2 = 0; n2 < 6; ++n2)
                    o[m][n2] = __builtin_amdgcn_mfma_f32_16x16x32_bf16(pa0, vf[n2][0], o[m][n2], 0, 0, 0);
#pragma unroll
                for (int n2 = 0; n2 < 6; ++n2)
                    o[m][n2] = __builtin_amdgcn_mfma_f32_16x16x32_bf16(pa1, vf[n2][1], o[m][n2], 0, 0, 0);
            }
        }
        // epilogue
#pragma unroll
        for (int m = 0; m < 2; ++m) {
            float linv[4];
#pragma unroll
            for (int r = 0; r < 4; ++r) linv[r] = 1.0f / (lrow[m][r] + 1e-9f);
#pragma unroll
            for (int n2 = 0; n2 < 6; ++n2)
#pragma unroll
                for (int r = 0; r < 4; ++r)
                    yb[(size_t)(rbase + m * 16 + quad * 4 + r) * C_ + h * HS_ + n2 * 16 + col] =
                        (bf16)(o[m][n2][r] * linv[r]);
        }
    }
}

// ---------------------------------------------------------------------------
extern "C" void kernel_launch(void* const* d_in, const int* in_sizes, int n_in,
                              void* d_out, int out_size, void* d_ws, size_t ws_size,
                              hipStream_t stream) {
    (void)in_sizes; (void)n_in;
    const float* x      = (const float*)d_in[0];
    const float* W_attn = (const float*)d_in[1];
    const float* b_attn = (const float*)d_in[2];
    const float* W_proj = (const float*)d_in[3];
    const float* b_proj = (const float*)d_in[4];
    float* out = (float*)d_out;

    size_t e_wta = (size_t)QKN_ * C_;
    size_t e_wtp = (size_t)C_ * C_;
    // Path A (batched): Wt | qkv[8192][2304] | Vt[4][768][2048] | yb[8192][768]
    size_t a_qkv = e_wta + e_wtp;
    size_t a_vt  = a_qkv + (size_t)M_ * QKN_;
    size_t a_yb  = a_vt + (size_t)M_ * C_;
    size_t needA = (a_yb + (size_t)M_ * C_) * sizeof(bf16);   // 67.6 MB
    // Path B (per-batch): Wt | qkv[2048][2304] | Vt[768][2048] | yb[2048][768]
    size_t b_qkv = e_wta + e_wtp;
    size_t b_vt  = b_qkv + (size_t)T_ * QKN_;
    size_t b_yb  = b_vt + (size_t)T_ * C_;
    size_t needB = (b_yb + (size_t)T_ * C_) * sizeof(bf16);   // 20.4 MB

    if (ws_size >= needA) {
        bf16* Wt_attn = (bf16*)d_ws;
        bf16* Wt_proj = (bf16*)d_ws + e_wta;
        bf16* qkv     = (bf16*)d_ws + a_qkv;
        bf16* Vt      = (bf16*)d_ws + a_vt;
        bf16* yb      = (bf16*)d_ws + a_yb;
        transpose_kernel<<<dim3(QKN_ / 32, C_ / 32), dim3(32, 8), 0, stream>>>(W_attn, Wt_attn, C_, QKN_);
        transpose_kernel<<<dim3(C_ / 32, C_ / 32), dim3(32, 8), 0, stream>>>(W_proj, Wt_proj, C_, C_);
        gemm_bt<float, bf16><<<dim3(QKN_ / 128, M_ / 128), 256, 0, stream>>>(
            x, Wt_attn, b_attn, qkv, M_, QKN_, C_);
        v_transpose<<<dim3(C_ / 32, T_ / 32, B_), dim3(32, 8), 0, stream>>>(qkv, Vt);
        attn_kernel<<<dim3(8, H_, B_), 256, 0, stream>>>(qkv, Vt, yb);
        gemm_bt<bf16, float><<<dim3(C_ / 128, M_ / 128), 256, 0, stream>>>(
            yb, Wt_proj, b_proj, out, M_, C_, C_);
    } else if (ws_size >= needB) {
        bf16* Wt_attn = (bf16*)d_ws;
        bf16* Wt_proj = (bf16*)d_ws + e_wta;
        bf16* qkv     = (bf16*)d_ws + b_qkv;
        bf16* Vt      = (bf16*)d_ws + b_vt;
        bf16* yb      = (bf16*)d_ws + b_yb;
        transpose_kernel<<<dim3(QKN_ / 32, C_ / 32), dim3(32, 8), 0, stream>>>(W_attn, Wt_attn, C_, QKN_);
        transpose_kernel<<<dim3(C_ / 32, C_ / 32), dim3(32, 8), 0, stream>>>(W_proj, Wt_proj, C_, C_);
        for (int b = 0; b < B_; ++b) {
            const float* xb = x + (size_t)b * T_ * C_;
            float* outb     = out + (size_t)b * T_ * C_;
            gemm_bt<float, bf16><<<dim3(QKN_ / 128, T_ / 128), 256, 0, stream>>>(
                xb, Wt_attn, b_attn, qkv, T_, QKN_, C_);
            v_transpose<<<dim3(C_ / 32, T_ / 32, 1), dim3(32, 8), 0, stream>>>(qkv, Vt);
            attn_kernel<<<dim3(8, H_, 1), 256, 0, stream>>>(qkv, Vt, yb);
            gemm_bt<bf16, float><<<dim3(C_ / 128, T_ / 128), 256, 0, stream>>>(
                yb, Wt_proj, b_proj, outb, T_, C_, C_);
        }
    } else {
        sentinel_kernel<<<(out_size + 255) / 256, 256, 0, stream>>>(out, out_size);
    }
}

// Round 6
// 261.400 us; speedup vs baseline: 4.2332x; 1.0975x over previous
//
#include <hip/hip_runtime.h>

typedef __bf16 bf16;
typedef __attribute__((ext_vector_type(8))) __bf16 bf16x8;
typedef __attribute__((ext_vector_type(4))) float f32x4;

#define B_   4
#define T_   2048
#define C_   768
#define H_   8
#define HS_  96
#define M_   (B_ * T_)      /* 8192 */
#define QKN_ (3 * C_)       /* 2304 */

#define NEG_BIG (-1e30f)

// LDS strides (elements) chosen so b128 fragment reads are <=2-way conflicts
#define KSTR 104   /* 64x(96) K tile rows, padded 96->104 */
#define VSTR 72    /* 96x(64) Vt tile rows, padded 64->72 */
#define PSTR 72    /* 16x(64) P tile rows (per wave), padded 64->72 */

// ---------------------------------------------------------------------------
// Transpose + convert: W[R][Cn] (fp32) -> Wt[Cn][R] (bf16)
// ---------------------------------------------------------------------------
__global__ void transpose_kernel(const float* __restrict__ W, bf16* __restrict__ Wt,
                                 int R, int Cn) {
    __shared__ bf16 tile[32][33];
    int tx = threadIdx.x, ty = threadIdx.y;
    int x  = blockIdx.x * 32 + tx;
    int y0 = blockIdx.y * 32;
#pragma unroll
    for (int j = 0; j < 32; j += 8)
        tile[ty + j][tx] = (bf16)W[(size_t)(y0 + ty + j) * Cn + x];
    __syncthreads();
    int y2 = blockIdx.x * 32;
    int x2 = y0 + tx;
#pragma unroll
    for (int j = 0; j < 32; j += 8)
        Wt[(size_t)(y2 + ty + j) * R + x2] = tile[tx][ty + j];
}

// ---------------------------------------------------------------------------
// V-part transpose: qkv[b][t][2C + c] -> Vt[b][c][t]   (c in [0,768))
// ---------------------------------------------------------------------------
__global__ void v_transpose(const bf16* __restrict__ qkv, bf16* __restrict__ Vt) {
    __shared__ bf16 tile[32][33];
    int b = blockIdx.z;
    const bf16* src = qkv + (size_t)b * T_ * QKN_ + 2 * C_;
    bf16* dst = Vt + (size_t)b * C_ * T_;
    int tx = threadIdx.x, ty = threadIdx.y;
    int cc = blockIdx.x * 32;
    int tt = blockIdx.y * 32;
#pragma unroll
    for (int j = 0; j < 32; j += 8)
        tile[ty + j][tx] = src[(size_t)(tt + ty + j) * QKN_ + cc + tx];
    __syncthreads();
#pragma unroll
    for (int j = 0; j < 32; j += 8)
        dst[(size_t)(cc + ty + j) * T_ + tt + tx] = tile[tx][ty + j];
}

// ---------------------------------------------------------------------------
__global__ void sentinel_kernel(float* __restrict__ out, int n) {
    int i = blockIdx.x * 256 + threadIdx.x;
    if (i < n) out[i] = 12345.0f;
}

// ---------------------------------------------------------------------------
__device__ __forceinline__ bf16x8 load8(const bf16* p) { return *(const bf16x8*)p; }
__device__ __forceinline__ bf16x8 load8(const float* p) {
    f32x4 v0 = *(const f32x4*)p;
    f32x4 v1 = *(const f32x4*)(p + 4);
    bf16x8 o;
#pragma unroll
    for (int i = 0; i < 4; ++i) { o[i] = (bf16)v0[i]; o[4 + i] = (bf16)v1[i]; }
    return o;
}
__device__ __forceinline__ void store1(bf16* p, float v)  { *p = (bf16)v; }
__device__ __forceinline__ void store1(float* p, float v) { *p = v; }

// ---------------------------------------------------------------------------
// C[M][N] = A[M][K] @ Bt[N][K]^T + bias[N]
// ---------------------------------------------------------------------------
template <typename AT, typename CT>
__global__ __launch_bounds__(256) void gemm_bt(const AT* __restrict__ A,
                                               const bf16* __restrict__ Bt,
                                               const float* __restrict__ bias,
                                               CT* __restrict__ Cmat,
                                               int M, int N, int K) {
    __shared__ bf16 lda[128 * 72];
    __shared__ bf16 ldb[128 * 72];
    int tid  = threadIdx.x;
    int w    = tid >> 6;
    int lane = tid & 63;
    int col  = lane & 15, quad = lane >> 4;
    int wr   = w >> 1, wc = w & 1;
    int m0   = blockIdx.y * 128, n0 = blockIdx.x * 128;

    const f32x4 zero = {0.f, 0.f, 0.f, 0.f};
    f32x4 acc[4][4];
#pragma unroll
    for (int mr = 0; mr < 4; ++mr)
#pragma unroll
        for (int nc = 0; nc < 4; ++nc) acc[mr][nc] = zero;

    for (int k0 = 0; k0 < K; k0 += 64) {
#pragma unroll
        for (int i = 0; i < 4; ++i) {
            int chunk = i * 256 + tid;
            int r = chunk >> 3, cc = chunk & 7;
            *(bf16x8*)&lda[r * 72 + cc * 8] = load8(&A[(size_t)(m0 + r) * K + k0 + cc * 8]);
            *(bf16x8*)&ldb[r * 72 + cc * 8] = load8(&Bt[(size_t)(n0 + r) * K + k0 + cc * 8]);
        }
        __syncthreads();
#pragma unroll
        for (int ks = 0; ks < 2; ++ks) {
            bf16x8 af[4], bfr[4];
#pragma unroll
            for (int t = 0; t < 4; ++t) {
                af[t]  = *(const bf16x8*)&lda[(wr * 64 + t * 16 + col) * 72 + ks * 32 + quad * 8];
                bfr[t] = *(const bf16x8*)&ldb[(wc * 64 + t * 16 + col) * 72 + ks * 32 + quad * 8];
            }
#pragma unroll
            for (int mr = 0; mr < 4; ++mr)
#pragma unroll
                for (int nc = 0; nc < 4; ++nc)
                    acc[mr][nc] = __builtin_amdgcn_mfma_f32_16x16x32_bf16(
                        af[mr], bfr[nc], acc[mr][nc], 0, 0, 0);
        }
        __syncthreads();
    }

#pragma unroll
    for (int nc = 0; nc < 4; ++nc) {
        int n = n0 + wc * 64 + nc * 16 + col;
        float bv = bias[n];
#pragma unroll
        for (int mr = 0; mr < 4; ++mr) {
#pragma unroll
            for (int r = 0; r < 4; ++r) {
                int row = m0 + wr * 64 + mr * 16 + quad * 4 + r;
                store1(&Cmat[(size_t)row * N + n], acc[mr][nc][r] + bv);
            }
        }
    }
}

// ---------------------------------------------------------------------------
// Fused causal flash attention, occupancy-oriented.
// Grid: 32 * nGroups blocks (1D), nGroups = H*B. Heavy-first: qt = 31 - bid/nG.
// Block: 256 thr (4 waves) owns 64 Q-rows (16/wave). j-tiles of 64; K/Vt in
// LDS shared by the 4 waves; per-wave P buffer (no extra barriers).
// ---------------------------------------------------------------------------
__global__ __launch_bounds__(256) void attn_kernel(const bf16* __restrict__ qkv,
                                                   const bf16* __restrict__ Vt,
                                                   bf16* __restrict__ y,
                                                   int nGroups) {
    __shared__ bf16 ldsK[64 * KSTR];
    __shared__ bf16 ldsV[96 * VSTR];
    __shared__ bf16 ldsP[4 * 16 * PSTR];
    const int bid  = blockIdx.x;
    const int qt   = 31 - bid / nGroups;      // heavy blocks dispatch first
    const int g    = bid % nGroups;
    const int h    = g & 7, b = g >> 3;
    const int tid  = threadIdx.x;
    const int w    = tid >> 6, lane = tid & 63;
    const int col  = lane & 15, quad = lane >> 4;
    const float scale = 0.10206207261596577f;   // 1/sqrt(96)
    const f32x4 zero = {0.f, 0.f, 0.f, 0.f};

    const bf16* qkvb = qkv + (size_t)b * T_ * QKN_;
    const bf16* Vtbh = Vt + (size_t)(b * H_ + h) * HS_ * T_;
    bf16* yb  = y + (size_t)b * T_ * C_;
    bf16* myP = &ldsP[w * 16 * PSTR];

    const int rbase = qt * 64 + w * 16;

    // Q fragments (A-layout, direct from global; contiguous in k)
    bf16x8 qf[3];
#pragma unroll
    for (int c = 0; c < 3; ++c)
        qf[c] = *(const bf16x8*)&qkvb[(size_t)(rbase + col) * QKN_ + h * HS_ + c * 32 + quad * 8];

    f32x4 o[6];
#pragma unroll
    for (int n2 = 0; n2 < 6; ++n2) o[n2] = zero;
    float mrow[4], lrow[4];
#pragma unroll
    for (int r = 0; r < 4; ++r) { mrow[r] = NEG_BIG; lrow[r] = 0.f; }

    const int njt = qt + 1;
    for (int jt = 0; jt < njt; ++jt) {
        int jb = jt * 64;
        __syncthreads();   // all waves done reading previous K/V
        // Stage K tile [64][96] and Vt tile [96][64]
#pragma unroll
        for (int i = 0; i < 3; ++i) {
            int chunk = i * 256 + tid;           // 768 chunks of 8 elems each
            int r  = chunk / 12, cc = chunk - r * 12;
            *(bf16x8*)&ldsK[r * KSTR + cc * 8] =
                *(const bf16x8*)&qkvb[(size_t)(jb + r) * QKN_ + C_ + h * HS_ + cc * 8];
            int r2 = chunk >> 3, c2 = chunk & 7;
            *(bf16x8*)&ldsV[r2 * VSTR + c2 * 8] =
                *(const bf16x8*)&Vtbh[(size_t)r2 * T_ + jb + c2 * 8];
        }
        __syncthreads();

        // S = Q K^T over four 16-col blocks
        bf16x8 kf[4][3];
#pragma unroll
        for (int nb = 0; nb < 4; ++nb)
#pragma unroll
            for (int c = 0; c < 3; ++c)
                kf[nb][c] = *(const bf16x8*)&ldsK[(nb * 16 + col) * KSTR + c * 32 + quad * 8];

        f32x4 sblk[4];
#pragma unroll
        for (int nb = 0; nb < 4; ++nb) sblk[nb] = zero;
#pragma unroll
        for (int c = 0; c < 3; ++c)
#pragma unroll
            for (int nb = 0; nb < 4; ++nb)
                sblk[nb] = __builtin_amdgcn_mfma_f32_16x16x32_bf16(
                    qf[c], kf[nb][c], sblk[nb], 0, 0, 0);

        if (jt == njt - 1) {                     // diagonal tile: causal mask
#pragma unroll
            for (int nb = 0; nb < 4; ++nb)
#pragma unroll
                for (int r = 0; r < 4; ++r) {
                    int ig = rbase + quad * 4 + r;
                    int jg = jb + nb * 16 + col;
                    sblk[nb][r] = (jg <= ig) ? sblk[nb][r] * scale : NEG_BIG;
                }
        } else {
#pragma unroll
            for (int nb = 0; nb < 4; ++nb)
#pragma unroll
                for (int r = 0; r < 4; ++r) sblk[nb][r] *= scale;
        }

        // Online softmax (rows live across 16-lane groups)
        float alpha[4];
#pragma unroll
        for (int r = 0; r < 4; ++r) {
            float mx = fmaxf(fmaxf(sblk[0][r], sblk[1][r]),
                             fmaxf(sblk[2][r], sblk[3][r]));
#pragma unroll
            for (int off = 1; off < 16; off <<= 1) mx = fmaxf(mx, __shfl_xor(mx, off, 64));
            float mnew = fmaxf(mrow[r], mx);
            float sum = 0.f;
#pragma unroll
            for (int nb = 0; nb < 4; ++nb) {
                float p = __expf(sblk[nb][r] - mnew);
                sblk[nb][r] = p;
                sum += p;
            }
#pragma unroll
            for (int off = 1; off < 16; off <<= 1) sum += __shfl_xor(sum, off, 64);
            alpha[r] = __expf(mrow[r] - mnew);
            lrow[r] = lrow[r] * alpha[r] + sum;
            mrow[r] = mnew;
        }

        // P -> per-wave LDS (C-layout -> A-layout round trip), rescale O
#pragma unroll
        for (int nb = 0; nb < 4; ++nb)
#pragma unroll
            for (int r = 0; r < 4; ++r)
                myP[(quad * 4 + r) * PSTR + nb * 16 + col] = (bf16)sblk[nb][r];
#pragma unroll
        for (int n2 = 0; n2 < 6; ++n2)
#pragma unroll
            for (int r = 0; r < 4; ++r) o[n2][r] *= alpha[r];

        // O += P @ V
        bf16x8 vf[6][2];
#pragma unroll
        for (int n2 = 0; n2 < 6; ++n2)
#pragma unroll
            for (int c = 0; c < 2; ++c)
                vf[n2][c] = *(const bf16x8*)&ldsV[(n2 * 16 + col) * VSTR + c * 32 + quad * 8];
        bf16x8 pa0 = *(const bf16x8*)&myP[col * PSTR + quad * 8];
        bf16x8 pa1 = *(const bf16x8*)&myP[col * PSTR + 32 + quad * 8];
#pragma unroll
        for (int n2 = 0; n2 < 6; ++n2)
            o[n2] = __builtin_amdgcn_mfma_f32_16x16x32_bf16(pa0, vf[n2][0], o[n2], 0, 0, 0);
#pragma unroll
        for (int n2 = 0; n2 < 6; ++n2)
            o[n2] = __builtin_amdgcn_mfma_f32_16x16x32_bf16(pa1, vf[n2][1], o[n2], 0, 0, 0);
    }

    // Epilogue: divide by (l + 1e-9), store y
    float linv[4];
#pragma unroll
    for (int r = 0; r < 4; ++r) linv[r] = 1.0f / (lrow[r] + 1e-9f);
#pragma unroll
    for (int n2 = 0; n2 < 6; ++n2)
#pragma unroll
        for (int r = 0; r < 4; ++r)
            yb[(size_t)(rbase + quad * 4 + r) * C_ + h * HS_ + n2 * 16 + col] =
                (bf16)(o[n2][r] * linv[r]);
}

// ---------------------------------------------------------------------------
extern "C" void kernel_launch(void* const* d_in, const int* in_sizes, int n_in,
                              void* d_out, int out_size, void* d_ws, size_t ws_size,
                              hipStream_t stream) {
    (void)in_sizes; (void)n_in;
    const float* x      = (const float*)d_in[0];
    const float* W_attn = (const float*)d_in[1];
    const float* b_attn = (const float*)d_in[2];
    const float* W_proj = (const float*)d_in[3];
    const float* b_proj = (const float*)d_in[4];
    float* out = (float*)d_out;

    size_t e_wta = (size_t)QKN_ * C_;
    size_t e_wtp = (size_t)C_ * C_;
    // Path A (batched): Wt | qkv[8192][2304] | Vt[4][768][2048] | yb[8192][768]
    size_t a_qkv = e_wta + e_wtp;
    size_t a_vt  = a_qkv + (size_t)M_ * QKN_;
    size_t a_yb  = a_vt + (size_t)M_ * C_;
    size_t needA = (a_yb + (size_t)M_ * C_) * sizeof(bf16);   // 67.6 MB
    // Path B (per-batch): Wt | qkv[2048][2304] | Vt[768][2048] | yb[2048][768]
    size_t b_qkv = e_wta + e_wtp;
    size_t b_vt  = b_qkv + (size_t)T_ * QKN_;
    size_t b_yb  = b_vt + (size_t)T_ * C_;
    size_t needB = (b_yb + (size_t)T_ * C_) * sizeof(bf16);   // 20.4 MB

    if (ws_size >= needA) {
        bf16* Wt_attn = (bf16*)d_ws;
        bf16* Wt_proj = (bf16*)d_ws + e_wta;
        bf16* qkv     = (bf16*)d_ws + a_qkv;
        bf16* Vt      = (bf16*)d_ws + a_vt;
        bf16* yb      = (bf16*)d_ws + a_yb;
        transpose_kernel<<<dim3(QKN_ / 32, C_ / 32), dim3(32, 8), 0, stream>>>(W_attn, Wt_attn, C_, QKN_);
        transpose_kernel<<<dim3(C_ / 32, C_ / 32), dim3(32, 8), 0, stream>>>(W_proj, Wt_proj, C_, C_);
        gemm_bt<float, bf16><<<dim3(QKN_ / 128, M_ / 128), 256, 0, stream>>>(
            x, Wt_attn, b_attn, qkv, M_, QKN_, C_);
        v_transpose<<<dim3(C_ / 32, T_ / 32, B_), dim3(32, 8), 0, stream>>>(qkv, Vt);
        attn_kernel<<<dim3(32 * H_ * B_), 256, 0, stream>>>(qkv, Vt, yb, H_ * B_);
        gemm_bt<bf16, float><<<dim3(C_ / 128, M_ / 128), 256, 0, stream>>>(
            yb, Wt_proj, b_proj, out, M_, C_, C_);
    } else if (ws_size >= needB) {
        bf16* Wt_attn = (bf16*)d_ws;
        bf16* Wt_proj = (bf16*)d_ws + e_wta;
        bf16* qkv     = (bf16*)d_ws + b_qkv;
        bf16* Vt      = (bf16*)d_ws + b_vt;
        bf16* yb      = (bf16*)d_ws + b_yb;
        transpose_kernel<<<dim3(QKN_ / 32, C_ / 32), dim3(32, 8), 0, stream>>>(W_attn, Wt_attn, C_, QKN_);
        transpose_kernel<<<dim3(C_ / 32, C_ / 32), dim3(32, 8), 0, stream>>>(W_proj, Wt_proj, C_, C_);
        for (int b = 0; b < B_; ++b) {
            const float* xb = x + (size_t)b * T_ * C_;
            float* outb     = out + (size_t)b * T_ * C_;
            gemm_bt<float, bf16><<<dim3(QKN_ / 128, T_ / 128), 256, 0, stream>>>(
                xb, Wt_attn, b_attn, qkv, T_, QKN_, C_);
            v_transpose<<<dim3(C_ / 32, T_ / 32, 1), dim3(32, 8), 0, stream>>>(qkv, Vt);
            attn_kernel<<<dim3(32 * H_), 256, 0, stream>>>(qkv, Vt, yb, H_);
            gemm_bt<bf16, float><<<dim3(C_ / 128, T_ / 128), 256, 0, stream>>>(
                yb, Wt_proj, b_proj, outb, T_, C_, C_);
        }
    } else {
        sentinel_kernel<<<(out_size + 255) / 256, 256, 0, stream>>>(out, out_size);
    }
}

// Round 7
// 242.424 us; speedup vs baseline: 4.5646x; 1.0783x over previous
//
#include <hip/hip_runtime.h>

typedef __bf16 bf16;
typedef __attribute__((ext_vector_type(4))) __bf16 bf16x4;
typedef __attribute__((ext_vector_type(8))) __bf16 bf16x8;
typedef __attribute__((ext_vector_type(4))) float f32x4;

#define B_   4
#define T_   2048
#define C_   768
#define H_   8
#define HS_  96
#define M_   (B_ * T_)      /* 8192 */
#define QKN_ (3 * C_)       /* 2304 */

#define NEG_BIG (-1e30f)

// LDS strides (elements) chosen so b128 fragment reads are <=2-way conflicts
#define KSTR 104   /* 64x(96) K tile rows, padded 96->104 */
#define VSTR 72    /* 96x(64) Vt tile rows, padded 64->72 */
#define PSTR 72    /* 16x(64) P tile rows (per wave), padded 64->72 */

// ---------------------------------------------------------------------------
// Transpose + convert: W[R][Cn] (fp32) -> Wt[Cn][R] (bf16)
// ---------------------------------------------------------------------------
__global__ void transpose_kernel(const float* __restrict__ W, bf16* __restrict__ Wt,
                                 int R, int Cn) {
    __shared__ bf16 tile[32][33];
    int tx = threadIdx.x, ty = threadIdx.y;
    int x  = blockIdx.x * 32 + tx;
    int y0 = blockIdx.y * 32;
#pragma unroll
    for (int j = 0; j < 32; j += 8)
        tile[ty + j][tx] = (bf16)W[(size_t)(y0 + ty + j) * Cn + x];
    __syncthreads();
    int y2 = blockIdx.x * 32;
    int x2 = y0 + tx;
#pragma unroll
    for (int j = 0; j < 32; j += 8)
        Wt[(size_t)(y2 + ty + j) * R + x2] = tile[tx][ty + j];
}

// ---------------------------------------------------------------------------
// V-part transpose: qkv[b][t][2C + c] -> Vt[b][c][t]   (c in [0,768))
// ---------------------------------------------------------------------------
__global__ void v_transpose(const bf16* __restrict__ qkv, bf16* __restrict__ Vt) {
    __shared__ bf16 tile[32][33];
    int b = blockIdx.z;
    const bf16* src = qkv + (size_t)b * T_ * QKN_ + 2 * C_;
    bf16* dst = Vt + (size_t)b * C_ * T_;
    int tx = threadIdx.x, ty = threadIdx.y;
    int cc = blockIdx.x * 32;
    int tt = blockIdx.y * 32;
#pragma unroll
    for (int j = 0; j < 32; j += 8)
        tile[ty + j][tx] = src[(size_t)(tt + ty + j) * QKN_ + cc + tx];
    __syncthreads();
#pragma unroll
    for (int j = 0; j < 32; j += 8)
        dst[(size_t)(cc + ty + j) * T_ + tt + tx] = tile[tx][ty + j];
}

// ---------------------------------------------------------------------------
__global__ void sentinel_kernel(float* __restrict__ out, int n) {
    int i = blockIdx.x * 256 + threadIdx.x;
    if (i < n) out[i] = 12345.0f;
}

// ---------------------------------------------------------------------------
__device__ __forceinline__ bf16x8 load8(const bf16* p) { return *(const bf16x8*)p; }
__device__ __forceinline__ bf16x8 load8(const float* p) {
    f32x4 v0 = *(const f32x4*)p;
    f32x4 v1 = *(const f32x4*)(p + 4);
    bf16x8 o;
#pragma unroll
    for (int i = 0; i < 4; ++i) { o[i] = (bf16)v0[i]; o[4 + i] = (bf16)v1[i]; }
    return o;
}
__device__ __forceinline__ void store1(bf16* p, float v)  { *p = (bf16)v; }
__device__ __forceinline__ void store1(float* p, float v) { *p = v; }

// ---------------------------------------------------------------------------
// C[M][N] = A[M][K] @ Bt[N][K]^T + bias[N]
// ---------------------------------------------------------------------------
template <typename AT, typename CT>
__global__ __launch_bounds__(256) void gemm_bt(const AT* __restrict__ A,
                                               const bf16* __restrict__ Bt,
                                               const float* __restrict__ bias,
                                               CT* __restrict__ Cmat,
                                               int M, int N, int K) {
    __shared__ bf16 lda[128 * 72];
    __shared__ bf16 ldb[128 * 72];
    int tid  = threadIdx.x;
    int w    = tid >> 6;
    int lane = tid & 63;
    int col  = lane & 15, quad = lane >> 4;
    int wr   = w >> 1, wc = w & 1;
    int m0   = blockIdx.y * 128, n0 = blockIdx.x * 128;

    const f32x4 zero = {0.f, 0.f, 0.f, 0.f};
    f32x4 acc[4][4];
#pragma unroll
    for (int mr = 0; mr < 4; ++mr)
#pragma unroll
        for (int nc = 0; nc < 4; ++nc) acc[mr][nc] = zero;

    for (int k0 = 0; k0 < K; k0 += 64) {
#pragma unroll
        for (int i = 0; i < 4; ++i) {
            int chunk = i * 256 + tid;
            int r = chunk >> 3, cc = chunk & 7;
            *(bf16x8*)&lda[r * 72 + cc * 8] = load8(&A[(size_t)(m0 + r) * K + k0 + cc * 8]);
            *(bf16x8*)&ldb[r * 72 + cc * 8] = load8(&Bt[(size_t)(n0 + r) * K + k0 + cc * 8]);
        }
        __syncthreads();
#pragma unroll
        for (int ks = 0; ks < 2; ++ks) {
            bf16x8 af[4], bfr[4];
#pragma unroll
            for (int t = 0; t < 4; ++t) {
                af[t]  = *(const bf16x8*)&lda[(wr * 64 + t * 16 + col) * 72 + ks * 32 + quad * 8];
                bfr[t] = *(const bf16x8*)&ldb[(wc * 64 + t * 16 + col) * 72 + ks * 32 + quad * 8];
            }
#pragma unroll
            for (int mr = 0; mr < 4; ++mr)
#pragma unroll
                for (int nc = 0; nc < 4; ++nc)
                    acc[mr][nc] = __builtin_amdgcn_mfma_f32_16x16x32_bf16(
                        af[mr], bfr[nc], acc[mr][nc], 0, 0, 0);
        }
        __syncthreads();
    }

#pragma unroll
    for (int nc = 0; nc < 4; ++nc) {
        int n = n0 + wc * 64 + nc * 16 + col;
        float bv = bias[n];
#pragma unroll
        for (int mr = 0; mr < 4; ++mr) {
#pragma unroll
            for (int r = 0; r < 4; ++r) {
                int row = m0 + wr * 64 + mr * 16 + quad * 4 + r;
                store1(&Cmat[(size_t)row * N + n], acc[mr][nc][r] + bv);
            }
        }
    }
}

// ---------------------------------------------------------------------------
// Fused causal flash attention, uniform-load version.
// Grid: 16 * nGroups blocks. Block (pair p, group g) processes qt = 31-p then
// qt = p  ->  exactly 33 j-tile steps per block (no tail imbalance).
// Block: 256 thr (4 waves), wave owns 16 Q-rows. j-tile = 64.
// Softmax computed on S^T (St = mfma(kf, qf)): j-reduction is in-lane +
// 2 cross-quad shuffles; P written to LDS as packed b64; exp2 domain.
// ---------------------------------------------------------------------------
__global__ __launch_bounds__(256) void attn_kernel(const bf16* __restrict__ qkv,
                                                   const bf16* __restrict__ Vt,
                                                   bf16* __restrict__ y,
                                                   int nGroups) {
    __shared__ bf16 ldsK[64 * KSTR];
    __shared__ bf16 ldsV[96 * VSTR];
    __shared__ bf16 ldsP[4 * 16 * PSTR];
    const int bid  = blockIdx.x;
    const int p    = bid / nGroups;           // 0..15
    const int g    = bid % nGroups;
    const int h    = g & 7, b = g >> 3;
    const int tid  = threadIdx.x;
    const int w    = tid >> 6, lane = tid & 63;
    const int col  = lane & 15, quad = lane >> 4;
    // scale * log2(e): softmax done in exp2 domain
    const float SCALE2 = 0.10206207261596577f * 1.4426950408889634f;
    const f32x4 zero = {0.f, 0.f, 0.f, 0.f};

    const bf16* qkvb = qkv + (size_t)b * T_ * QKN_;
    const bf16* Vtbh = Vt + (size_t)(b * H_ + h) * HS_ * T_;
    bf16* yb  = y + (size_t)b * T_ * C_;
    bf16* myP = &ldsP[w * 16 * PSTR];

#pragma unroll
    for (int half = 0; half < 2; ++half) {
        const int qt    = half ? p : (31 - p);
        const int rbase = qt * 64 + w * 16;

        // Q fragments (B-operand layout == A layout indexing; contiguous in k)
        bf16x8 qf[3];
#pragma unroll
        for (int c = 0; c < 3; ++c)
            qf[c] = *(const bf16x8*)&qkvb[(size_t)(rbase + col) * QKN_ + h * HS_ + c * 32 + quad * 8];

        f32x4 o[6];
#pragma unroll
        for (int n2 = 0; n2 < 6; ++n2) o[n2] = zero;
        float mrow = NEG_BIG, lrow = 0.f;    // per-lane state for query i = col

        const int njt = qt + 1;
        for (int jt = 0; jt < njt; ++jt) {
            int jb = jt * 64;
            __syncthreads();   // all waves done reading previous K/V
            // Stage K tile [64][96] and Vt tile [96][64]
#pragma unroll
            for (int i = 0; i < 3; ++i) {
                int chunk = i * 256 + tid;           // 768 chunks of 8 elems each
                int r  = chunk / 12, cc = chunk - r * 12;
                *(bf16x8*)&ldsK[r * KSTR + cc * 8] =
                    *(const bf16x8*)&qkvb[(size_t)(jb + r) * QKN_ + C_ + h * HS_ + cc * 8];
                int r2 = chunk >> 3, c2 = chunk & 7;
                *(bf16x8*)&ldsV[r2 * VSTR + c2 * 8] =
                    *(const bf16x8*)&Vtbh[(size_t)r2 * T_ + jb + c2 * 8];
            }
            __syncthreads();

            // St = K Q^T  (D[m=j_local][n=i]); four 16-row j-blocks
            bf16x8 kf[4][3];
#pragma unroll
            for (int nb = 0; nb < 4; ++nb)
#pragma unroll
                for (int c = 0; c < 3; ++c)
                    kf[nb][c] = *(const bf16x8*)&ldsK[(nb * 16 + col) * KSTR + c * 32 + quad * 8];

            f32x4 st[4];
#pragma unroll
            for (int nb = 0; nb < 4; ++nb) st[nb] = zero;
#pragma unroll
            for (int c = 0; c < 3; ++c)
#pragma unroll
                for (int nb = 0; nb < 4; ++nb)
                    st[nb] = __builtin_amdgcn_mfma_f32_16x16x32_bf16(
                        kf[nb][c], qf[c], st[nb], 0, 0, 0);

            // scale (exp2 domain) + causal mask on the diagonal tile.
            // lane holds St[j = jb + nb*16 + quad*4 + r][i = rbase + col]
            if (jt == njt - 1) {
#pragma unroll
                for (int nb = 0; nb < 4; ++nb)
#pragma unroll
                    for (int r = 0; r < 4; ++r) {
                        int jg = jb + nb * 16 + quad * 4 + r;
                        st[nb][r] = (jg <= rbase + col) ? st[nb][r] * SCALE2 : NEG_BIG;
                    }
            } else {
#pragma unroll
                for (int nb = 0; nb < 4; ++nb)
#pragma unroll
                    for (int r = 0; r < 4; ++r) st[nb][r] *= SCALE2;
            }

            // softmax over j for query i=col: in-lane (16 vals) + cross-quad
            float mx = st[0][0];
#pragma unroll
            for (int nb = 0; nb < 4; ++nb)
#pragma unroll
                for (int r = 0; r < 4; ++r) mx = fmaxf(mx, st[nb][r]);
            mx = fmaxf(mx, __shfl_xor(mx, 16, 64));
            mx = fmaxf(mx, __shfl_xor(mx, 32, 64));
            float mnew = fmaxf(mrow, mx);
            float sum = 0.f;
#pragma unroll
            for (int nb = 0; nb < 4; ++nb)
#pragma unroll
                for (int r = 0; r < 4; ++r) {
                    float pv = exp2f(st[nb][r] - mnew);
                    st[nb][r] = pv;
                    sum += pv;
                }
            sum += __shfl_xor(sum, 16, 64);
            sum += __shfl_xor(sum, 32, 64);
            float alpha = exp2f(mrow - mnew);
            lrow = lrow * alpha + sum;
            mrow = mnew;

            // P[i=col][j] -> per-wave LDS, packed 4x bf16 (b64 stores)
#pragma unroll
            for (int nb = 0; nb < 4; ++nb) {
                bf16x4 pk = {(bf16)st[nb][0], (bf16)st[nb][1],
                             (bf16)st[nb][2], (bf16)st[nb][3]};
                *(bf16x4*)&myP[col * PSTR + nb * 16 + quad * 4] = pk;
            }
            // redistribute alpha to O-layout rows (i = quad*4 + r), rescale O
#pragma unroll
            for (int r = 0; r < 4; ++r) {
                float ar = __shfl(alpha, quad * 4 + r, 16);
#pragma unroll
                for (int n2 = 0; n2 < 6; ++n2) o[n2][r] *= ar;
            }

            // O += P @ V
            bf16x8 vf[6][2];
#pragma unroll
            for (int n2 = 0; n2 < 6; ++n2)
#pragma unroll
                for (int c = 0; c < 2; ++c)
                    vf[n2][c] = *(const bf16x8*)&ldsV[(n2 * 16 + col) * VSTR + c * 32 + quad * 8];
            bf16x8 pa0 = *(const bf16x8*)&myP[col * PSTR + quad * 8];
            bf16x8 pa1 = *(const bf16x8*)&myP[col * PSTR + 32 + quad * 8];
#pragma unroll
            for (int n2 = 0; n2 < 6; ++n2)
                o[n2] = __builtin_amdgcn_mfma_f32_16x16x32_bf16(pa0, vf[n2][0], o[n2], 0, 0, 0);
#pragma unroll
            for (int n2 = 0; n2 < 6; ++n2)
                o[n2] = __builtin_amdgcn_mfma_f32_16x16x32_bf16(pa1, vf[n2][1], o[n2], 0, 0, 0);
        }

        // Epilogue: divide by (l + 1e-9), store y
        float linv_self = 1.0f / (lrow + 1e-9f);
        float linv[4];
#pragma unroll
        for (int r = 0; r < 4; ++r) linv[r] = __shfl(linv_self, quad * 4 + r, 16);
#pragma unroll
        for (int n2 = 0; n2 < 6; ++n2)
#pragma unroll
            for (int r = 0; r < 4; ++r)
                yb[(size_t)(rbase + quad * 4 + r) * C_ + h * HS_ + n2 * 16 + col] =
                    (bf16)(o[n2][r] * linv[r]);
    }
}

// ---------------------------------------------------------------------------
extern "C" void kernel_launch(void* const* d_in, const int* in_sizes, int n_in,
                              void* d_out, int out_size, void* d_ws, size_t ws_size,
                              hipStream_t stream) {
    (void)in_sizes; (void)n_in;
    const float* x      = (const float*)d_in[0];
    const float* W_attn = (const float*)d_in[1];
    const float* b_attn = (const float*)d_in[2];
    const float* W_proj = (const float*)d_in[3];
    const float* b_proj = (const float*)d_in[4];
    float* out = (float*)d_out;

    size_t e_wta = (size_t)QKN_ * C_;
    size_t e_wtp = (size_t)C_ * C_;
    // Path A (batched): Wt | qkv[8192][2304] | Vt[4][768][2048] | yb[8192][768]
    size_t a_qkv = e_wta + e_wtp;
    size_t a_vt  = a_qkv + (size_t)M_ * QKN_;
    size_t a_yb  = a_vt + (size_t)M_ * C_;
    size_t needA = (a_yb + (size_t)M_ * C_) * sizeof(bf16);   // 67.6 MB
    // Path B (per-batch): Wt | qkv[2048][2304] | Vt[768][2048] | yb[2048][768]
    size_t b_qkv = e_wta + e_wtp;
    size_t b_vt  = b_qkv + (size_t)T_ * QKN_;
    size_t b_yb  = b_vt + (size_t)T_ * C_;
    size_t needB = (b_yb + (size_t)T_ * C_) * sizeof(bf16);   // 20.4 MB

    if (ws_size >= needA) {
        bf16* Wt_attn = (bf16*)d_ws;
        bf16* Wt_proj = (bf16*)d_ws + e_wta;
        bf16* qkv     = (bf16*)d_ws + a_qkv;
        bf16* Vt      = (bf16*)d_ws + a_vt;
        bf16* yb      = (bf16*)d_ws + a_yb;
        transpose_kernel<<<dim3(QKN_ / 32, C_ / 32), dim3(32, 8), 0, stream>>>(W_attn, Wt_attn, C_, QKN_);
        transpose_kernel<<<dim3(C_ / 32, C_ / 32), dim3(32, 8), 0, stream>>>(W_proj, Wt_proj, C_, C_);
        gemm_bt<float, bf16><<<dim3(QKN_ / 128, M_ / 128), 256, 0, stream>>>(
            x, Wt_attn, b_attn, qkv, M_, QKN_, C_);
        v_transpose<<<dim3(C_ / 32, T_ / 32, B_), dim3(32, 8), 0, stream>>>(qkv, Vt);
        attn_kernel<<<dim3(16 * H_ * B_), 256, 0, stream>>>(qkv, Vt, yb, H_ * B_);
        gemm_bt<bf16, float><<<dim3(C_ / 128, M_ / 128), 256, 0, stream>>>(
            yb, Wt_proj, b_proj, out, M_, C_, C_);
    } else if (ws_size >= needB) {
        bf16* Wt_attn = (bf16*)d_ws;
        bf16* Wt_proj = (bf16*)d_ws + e_wta;
        bf16* qkv     = (bf16*)d_ws + b_qkv;
        bf16* Vt      = (bf16*)d_ws + b_vt;
        bf16* yb      = (bf16*)d_ws + b_yb;
        transpose_kernel<<<dim3(QKN_ / 32, C_ / 32), dim3(32, 8), 0, stream>>>(W_attn, Wt_attn, C_, QKN_);
        transpose_kernel<<<dim3(C_ / 32, C_ / 32), dim3(32, 8), 0, stream>>>(W_proj, Wt_proj, C_, C_);
        for (int b = 0; b < B_; ++b) {
            const float* xb = x + (size_t)b * T_ * C_;
            float* outb     = out + (size_t)b * T_ * C_;
            gemm_bt<float, bf16><<<dim3(QKN_ / 128, T_ / 128), 256, 0, stream>>>(
                xb, Wt_attn, b_attn, qkv, T_, QKN_, C_);
            v_transpose<<<dim3(C_ / 32, T_ / 32, 1), dim3(32, 8), 0, stream>>>(qkv, Vt);
            attn_kernel<<<dim3(16 * H_), 256, 0, stream>>>(qkv, Vt, yb, H_);
            gemm_bt<bf16, float><<<dim3(C_ / 128, T_ / 128), 256, 0, stream>>>(
                yb, Wt_proj, b_proj, outb, T_, C_, C_);
        }
    } else {
        sentinel_kernel<<<(out_size + 255) / 256, 256, 0, stream>>>(out, out_size);
    }
}

// Round 8
// 239.552 us; speedup vs baseline: 4.6193x; 1.0120x over previous
//
#include <hip/hip_runtime.h>

typedef __bf16 bf16;
typedef __attribute__((ext_vector_type(4))) __bf16 bf16x4;
typedef __attribute__((ext_vector_type(8))) __bf16 bf16x8;
typedef __attribute__((ext_vector_type(4))) float f32x4;

#define B_   4
#define T_   2048
#define C_   768
#define H_   8
#define HS_  96
#define M_   (B_ * T_)      /* 8192 */
#define QKN_ (3 * C_)       /* 2304 */

#define NEG_BIG (-1e30f)

// LDS strides (elements) for attn tiles: b128 fragment reads <=2-way conflicts
#define KSTR 104   /* 64x(96) K tile rows, padded 96->104 */
#define VSTR 72    /* 96x(64) Vt tile rows, padded 64->72 */
#define PSTR 72    /* 16x(64) P tile rows (per wave), padded 64->72 */

// ---------------------------------------------------------------------------
// async global->LDS, 16B per lane. LDS dest must be wave-uniform base;
// HW writes lane i at base + i*16.  [m97 pattern]
// ---------------------------------------------------------------------------
__device__ __forceinline__ void gload16(const bf16* gp, bf16* lp) {
    __builtin_amdgcn_global_load_lds(
        (const __attribute__((address_space(1))) unsigned int*)gp,
        (__attribute__((address_space(3))) unsigned int*)lp, 16, 0, 0);
}

// ---------------------------------------------------------------------------
// Transpose + convert: W[R][Cn] (fp32) -> Wt[Cn][R] (bf16)
// ---------------------------------------------------------------------------
__global__ void transpose_kernel(const float* __restrict__ W, bf16* __restrict__ Wt,
                                 int R, int Cn) {
    __shared__ bf16 tile[32][33];
    int tx = threadIdx.x, ty = threadIdx.y;
    int x  = blockIdx.x * 32 + tx;
    int y0 = blockIdx.y * 32;
#pragma unroll
    for (int j = 0; j < 32; j += 8)
        tile[ty + j][tx] = (bf16)W[(size_t)(y0 + ty + j) * Cn + x];
    __syncthreads();
    int y2 = blockIdx.x * 32;
    int x2 = y0 + tx;
#pragma unroll
    for (int j = 0; j < 32; j += 8)
        Wt[(size_t)(y2 + ty + j) * R + x2] = tile[tx][ty + j];
}

// ---------------------------------------------------------------------------
// fp32 -> bf16 elementwise (x pre-conversion). n multiple of 1024.
// ---------------------------------------------------------------------------
__global__ void f2b_kernel(const float* __restrict__ in, bf16* __restrict__ out) {
    int i = (blockIdx.x * 256 + threadIdx.x) * 4;
    f32x4 v = *(const f32x4*)&in[i];
    bf16x4 o = {(bf16)v[0], (bf16)v[1], (bf16)v[2], (bf16)v[3]};
    *(bf16x4*)&out[i] = o;
}

// ---------------------------------------------------------------------------
// V-part transpose: qkv[b][t][2C + c] -> Vt[b][c][t]
// ---------------------------------------------------------------------------
__global__ void v_transpose(const bf16* __restrict__ qkv, bf16* __restrict__ Vt) {
    __shared__ bf16 tile[32][33];
    int b = blockIdx.z;
    const bf16* src = qkv + (size_t)b * T_ * QKN_ + 2 * C_;
    bf16* dst = Vt + (size_t)b * C_ * T_;
    int tx = threadIdx.x, ty = threadIdx.y;
    int cc = blockIdx.x * 32;
    int tt = blockIdx.y * 32;
#pragma unroll
    for (int j = 0; j < 32; j += 8)
        tile[ty + j][tx] = src[(size_t)(tt + ty + j) * QKN_ + cc + tx];
    __syncthreads();
#pragma unroll
    for (int j = 0; j < 32; j += 8)
        dst[(size_t)(cc + ty + j) * T_ + tt + tx] = tile[tx][ty + j];
}

// ---------------------------------------------------------------------------
__global__ void sentinel_kernel(float* __restrict__ out, int n) {
    int i = blockIdx.x * 256 + threadIdx.x;
    if (i < n) out[i] = 12345.0f;
}

// ---------------------------------------------------------------------------
__device__ __forceinline__ void store1(bf16* p, float v)  { *p = (bf16)v; }
__device__ __forceinline__ void store1(float* p, float v) { *p = v; }

// ---------------------------------------------------------------------------
// C[M][N] = A[M][K] @ Bt[N][K]^T + bias[N]   (bf16 in, fp32 accum)
// 128x128 tile, BK=64. m97-style: global_load_lds dwordx4, unpadded LDS.
// ---------------------------------------------------------------------------
template <typename CT>
__global__ __launch_bounds__(256) void gemm_bt(const bf16* __restrict__ A,
                                               const bf16* __restrict__ Bt,
                                               const float* __restrict__ bias,
                                               CT* __restrict__ Cmat,
                                               int M, int N, int K) {
    __shared__ bf16 lda[128 * 64];
    __shared__ bf16 ldb[128 * 64];
    int tid  = threadIdx.x;
    int w    = tid >> 6;
    int lane = tid & 63;
    int col  = lane & 15, quad = lane >> 4;
    int wr   = w >> 1, wc = w & 1;
    int m0   = blockIdx.y * 128, n0 = blockIdx.x * 128;

    const f32x4 zero = {0.f, 0.f, 0.f, 0.f};
    f32x4 acc[4][4];
#pragma unroll
    for (int mr = 0; mr < 4; ++mr)
#pragma unroll
        for (int nc = 0; nc < 4; ++nc) acc[mr][nc] = zero;

    for (int k0 = 0; k0 < K; k0 += 64) {
        // stage A and B tiles: 1024 16B-granules each (8 granules per 64-el row)
#pragma unroll
        for (int i = 0; i < 4; ++i) {
            int gbase = i * 256 + w * 64;      // wave-uniform granule base
            int g  = gbase + lane;
            int r  = g >> 3, cc = g & 7;
            gload16(&A[(size_t)(m0 + r) * K + k0 + cc * 8],  &lda[gbase * 8]);
            gload16(&Bt[(size_t)(n0 + r) * K + k0 + cc * 8], &ldb[gbase * 8]);
        }
        __syncthreads();
#pragma unroll
        for (int ks = 0; ks < 2; ++ks) {
            bf16x8 af[4], bfr[4];
#pragma unroll
            for (int t = 0; t < 4; ++t) {
                af[t]  = *(const bf16x8*)&lda[(wr * 64 + t * 16 + col) * 64 + ks * 32 + quad * 8];
                bfr[t] = *(const bf16x8*)&ldb[(wc * 64 + t * 16 + col) * 64 + ks * 32 + quad * 8];
            }
#pragma unroll
            for (int mr = 0; mr < 4; ++mr)
#pragma unroll
                for (int nc = 0; nc < 4; ++nc)
                    acc[mr][nc] = __builtin_amdgcn_mfma_f32_16x16x32_bf16(
                        af[mr], bfr[nc], acc[mr][nc], 0, 0, 0);
        }
        __syncthreads();
    }

#pragma unroll
    for (int nc = 0; nc < 4; ++nc) {
        int n = n0 + wc * 64 + nc * 16 + col;
        float bv = bias[n];
#pragma unroll
        for (int mr = 0; mr < 4; ++mr) {
#pragma unroll
            for (int r = 0; r < 4; ++r) {
                int row = m0 + wr * 64 + mr * 16 + quad * 4 + r;
                store1(&Cmat[(size_t)row * N + n], acc[mr][nc][r] + bv);
            }
        }
    }
}

// ---------------------------------------------------------------------------
// Fused causal flash attention, static-exponent softmax (no cross-lane ops in
// the loop). exp2 scaling by fixed M0 is EXACT (power of 2) and cancels in
// PV/l, so the result is the true softmax.
// Grid: 16*nGroups blocks, block (pair p) does qt=31-p then qt=p (33 steps).
// O is held transposed [hs][q] via mfma(vf, pa) so softmax state, l and O all
// live on lane q=col. Epilogue: 2-shuffle l-reduce, packed b64 y store.
// ---------------------------------------------------------------------------
__global__ __launch_bounds__(256) void attn_kernel(const bf16* __restrict__ qkv,
                                                   const bf16* __restrict__ Vt,
                                                   bf16* __restrict__ y,
                                                   int nGroups) {
    __shared__ bf16 ldsK[64 * KSTR];
    __shared__ bf16 ldsV[96 * VSTR];
    __shared__ bf16 ldsP[4 * 16 * PSTR];
    const int bid  = blockIdx.x;
    const int p    = bid / nGroups;           // 0..15
    const int g    = bid % nGroups;
    const int h    = g & 7, b = g >> 3;
    const int tid  = threadIdx.x;
    const int w    = tid >> 6, lane = tid & 63;
    const int col  = lane & 15, quad = lane >> 4;
    const float SCALE2 = 0.10206207261596577f * 1.4426950408889634f; // scale*log2e
    const float M0 = 24.0f;                    // static exponent shift (exact)
    const f32x4 zero = {0.f, 0.f, 0.f, 0.f};

    const bf16* qkvb = qkv + (size_t)b * T_ * QKN_;
    const bf16* Vtbh = Vt + (size_t)(b * H_ + h) * HS_ * T_;
    bf16* yb  = y + (size_t)b * T_ * C_;
    bf16* myP = &ldsP[w * 16 * PSTR];

#pragma unroll
    for (int half = 0; half < 2; ++half) {
        const int qt    = half ? p : (31 - p);
        const int rbase = qt * 64 + w * 16;

        // Q fragments (B-operand layout; contiguous in k)
        bf16x8 qf[3];
#pragma unroll
        for (int c = 0; c < 3; ++c)
            qf[c] = *(const bf16x8*)&qkvb[(size_t)(rbase + col) * QKN_ + h * HS_ + c * 32 + quad * 8];

        f32x4 o[6];
#pragma unroll
        for (int n2 = 0; n2 < 6; ++n2) o[n2] = zero;
        float lsum = 0.f;                      // per-lane partial (query i=col)

        const int njt = qt + 1;
        for (int jt = 0; jt < njt; ++jt) {
            int jb = jt * 64;
            __syncthreads();   // all waves done reading previous K/V
            // Stage K tile [64][96] and Vt tile [96][64]
#pragma unroll
            for (int i = 0; i < 3; ++i) {
                int chunk = i * 256 + tid;
                int r  = chunk / 12, cc = chunk - r * 12;
                *(bf16x8*)&ldsK[r * KSTR + cc * 8] =
                    *(const bf16x8*)&qkvb[(size_t)(jb + r) * QKN_ + C_ + h * HS_ + cc * 8];
                int r2 = chunk >> 3, c2 = chunk & 7;
                *(bf16x8*)&ldsV[r2 * VSTR + c2 * 8] =
                    *(const bf16x8*)&Vtbh[(size_t)r2 * T_ + jb + c2 * 8];
            }
            __syncthreads();

            // St = K Q^T: lane holds St[j = jb+nb*16+quad*4+r][i = rbase+col]
            bf16x8 kf[4][3];
#pragma unroll
            for (int nb = 0; nb < 4; ++nb)
#pragma unroll
                for (int c = 0; c < 3; ++c)
                    kf[nb][c] = *(const bf16x8*)&ldsK[(nb * 16 + col) * KSTR + c * 32 + quad * 8];

            f32x4 st[4];
#pragma unroll
            for (int nb = 0; nb < 4; ++nb) st[nb] = zero;
#pragma unroll
            for (int c = 0; c < 3; ++c)
#pragma unroll
                for (int nb = 0; nb < 4; ++nb)
                    st[nb] = __builtin_amdgcn_mfma_f32_16x16x32_bf16(
                        kf[nb][c], qf[c], st[nb], 0, 0, 0);

            // scale to exp2 domain, subtract static M0; mask diagonal tile
            if (jt == njt - 1) {
#pragma unroll
                for (int nb = 0; nb < 4; ++nb)
#pragma unroll
                    for (int r = 0; r < 4; ++r) {
                        int jg = jb + nb * 16 + quad * 4 + r;
                        st[nb][r] = (jg <= rbase + col) ? fmaf(st[nb][r], SCALE2, -M0)
                                                        : NEG_BIG;
                    }
            } else {
#pragma unroll
                for (int nb = 0; nb < 4; ++nb)
#pragma unroll
                    for (int r = 0; r < 4; ++r)
                        st[nb][r] = fmaf(st[nb][r], SCALE2, -M0);
            }

            // p = exp2(st), per-lane partial sum; P -> per-wave LDS (b64)
#pragma unroll
            for (int nb = 0; nb < 4; ++nb) {
#pragma unroll
                for (int r = 0; r < 4; ++r) {
                    float pv = exp2f(st[nb][r]);
                    st[nb][r] = pv;
                    lsum += pv;
                }
                bf16x4 pk = {(bf16)st[nb][0], (bf16)st[nb][1],
                             (bf16)st[nb][2], (bf16)st[nb][3]};
                *(bf16x4*)&myP[col * PSTR + nb * 16 + quad * 4] = pk;
            }

            // Ot += V^T P^T  (A = Vt frag, B = P^T frag)
            bf16x8 vf[6][2];
#pragma unroll
            for (int n2 = 0; n2 < 6; ++n2)
#pragma unroll
                for (int c = 0; c < 2; ++c)
                    vf[n2][c] = *(const bf16x8*)&ldsV[(n2 * 16 + col) * VSTR + c * 32 + quad * 8];
            bf16x8 pa0 = *(const bf16x8*)&myP[col * PSTR + quad * 8];
            bf16x8 pa1 = *(const bf16x8*)&myP[col * PSTR + 32 + quad * 8];
#pragma unroll
            for (int n2 = 0; n2 < 6; ++n2)
                o[n2] = __builtin_amdgcn_mfma_f32_16x16x32_bf16(vf[n2][0], pa0, o[n2], 0, 0, 0);
#pragma unroll
            for (int n2 = 0; n2 < 6; ++n2)
                o[n2] = __builtin_amdgcn_mfma_f32_16x16x32_bf16(vf[n2][1], pa1, o[n2], 0, 0, 0);
        }

        // Epilogue: reduce l across the 4 quad-groups, normalize, store y.
        lsum += __shfl_xor(lsum, 16, 64);
        lsum += __shfl_xor(lsum, 32, 64);
        float linv = 1.0f / lsum;
        // lane holds Ot[hs = n2*16 + quad*4 + r][q = rbase + col]
#pragma unroll
        for (int n2 = 0; n2 < 6; ++n2) {
            bf16x4 pk = {(bf16)(o[n2][0] * linv), (bf16)(o[n2][1] * linv),
                         (bf16)(o[n2][2] * linv), (bf16)(o[n2][3] * linv)};
            *(bf16x4*)&yb[(size_t)(rbase + col) * C_ + h * HS_ + n2 * 16 + quad * 4] = pk;
        }
    }
}

// ---------------------------------------------------------------------------
extern "C" void kernel_launch(void* const* d_in, const int* in_sizes, int n_in,
                              void* d_out, int out_size, void* d_ws, size_t ws_size,
                              hipStream_t stream) {
    (void)in_sizes; (void)n_in;
    const float* x      = (const float*)d_in[0];
    const float* W_attn = (const float*)d_in[1];
    const float* b_attn = (const float*)d_in[2];
    const float* W_proj = (const float*)d_in[3];
    const float* b_proj = (const float*)d_in[4];
    float* out = (float*)d_out;

    size_t e_wta = (size_t)QKN_ * C_;
    size_t e_wtp = (size_t)C_ * C_;
    // Path A (batched): Wt | qkv[8192][2304] | Vt[4][768][2048] | yb[8192][768]
    size_t a_qkv = e_wta + e_wtp;
    size_t a_vt  = a_qkv + (size_t)M_ * QKN_;
    size_t a_yb  = a_vt + (size_t)M_ * C_;
    size_t needA = (a_yb + (size_t)M_ * C_) * sizeof(bf16);   // 67.6 MB
    // Path B (per-batch)
    size_t b_qkv = e_wta + e_wtp;
    size_t b_vt  = b_qkv + (size_t)T_ * QKN_;
    size_t b_yb  = b_vt + (size_t)T_ * C_;
    size_t needB = (b_yb + (size_t)T_ * C_) * sizeof(bf16);   // 20.4 MB

    if (ws_size >= needA) {
        bf16* Wt_attn = (bf16*)d_ws;
        bf16* Wt_proj = (bf16*)d_ws + e_wta;
        bf16* qkv     = (bf16*)d_ws + a_qkv;
        bf16* Vt      = (bf16*)d_ws + a_vt;
        bf16* yb      = (bf16*)d_ws + a_yb;
        // x (bf16) scratch inside d_out: 12.6 MB of its 25.2 MB; gemm2 fully
        // overwrites d_out afterwards.
        bf16* xb = (bf16*)d_out;
        transpose_kernel<<<dim3(QKN_ / 32, C_ / 32), dim3(32, 8), 0, stream>>>(W_attn, Wt_attn, C_, QKN_);
        transpose_kernel<<<dim3(C_ / 32, C_ / 32), dim3(32, 8), 0, stream>>>(W_proj, Wt_proj, C_, C_);
        f2b_kernel<<<dim3(M_ * C_ / 1024), 256, 0, stream>>>(x, xb);
        gemm_bt<bf16><<<dim3(QKN_ / 128, M_ / 128), 256, 0, stream>>>(
            xb, Wt_attn, b_attn, qkv, M_, QKN_, C_);
        v_transpose<<<dim3(C_ / 32, T_ / 32, B_), dim3(32, 8), 0, stream>>>(qkv, Vt);
        attn_kernel<<<dim3(16 * H_ * B_), 256, 0, stream>>>(qkv, Vt, yb, H_ * B_);
        gemm_bt<float><<<dim3(C_ / 128, M_ / 128), 256, 0, stream>>>(
            yb, Wt_proj, b_proj, out, M_, C_, C_);
    } else if (ws_size >= needB) {
        bf16* Wt_attn = (bf16*)d_ws;
        bf16* Wt_proj = (bf16*)d_ws + e_wta;
        bf16* qkv     = (bf16*)d_ws + b_qkv;
        bf16* Vt      = (bf16*)d_ws + b_vt;
        bf16* yb      = (bf16*)d_ws + b_yb;
        transpose_kernel<<<dim3(QKN_ / 32, C_ / 32), dim3(32, 8), 0, stream>>>(W_attn, Wt_attn, C_, QKN_);
        transpose_kernel<<<dim3(C_ / 32, C_ / 32), dim3(32, 8), 0, stream>>>(W_proj, Wt_proj, C_, C_);
        for (int b = 0; b < B_; ++b) {
            const float* xsrc = x + (size_t)b * T_ * C_;
            float* outb       = out + (size_t)b * T_ * C_;
            bf16* xb          = (bf16*)outb;   // per-batch scratch in d_out
            f2b_kernel<<<dim3(T_ * C_ / 1024), 256, 0, stream>>>(xsrc, xb);
            gemm_bt<bf16><<<dim3(QKN_ / 128, T_ / 128), 256, 0, stream>>>(
                xb, Wt_attn, b_attn, qkv, T_, QKN_, C_);
            v_transpose<<<dim3(C_ / 32, T_ / 32, 1), dim3(32, 8), 0, stream>>>(qkv, Vt);
            attn_kernel<<<dim3(16 * H_), 256, 0, stream>>>(qkv, Vt, yb, H_);
            gemm_bt<float><<<dim3(C_ / 128, T_ / 128), 256, 0, stream>>>(
                yb, Wt_proj, b_proj, outb, T_, C_, C_);
        }
    } else {
        sentinel_kernel<<<(out_size + 255) / 256, 256, 0, stream>>>(out, out_size);
    }
}

// Round 9
// 234.307 us; speedup vs baseline: 4.7227x; 1.0224x over previous
//
#include <hip/hip_runtime.h>

typedef __bf16 bf16;
typedef __attribute__((ext_vector_type(4))) __bf16 bf16x4;
typedef __attribute__((ext_vector_type(8))) __bf16 bf16x8;
typedef __attribute__((ext_vector_type(4))) float f32x4;

#define B_   4
#define T_   2048
#define C_   768
#define H_   8
#define HS_  96
#define M_   (B_ * T_)      /* 8192 */
#define QKN_ (3 * C_)       /* 2304 */

#define NEG_BIG (-1e30f)

// LDS strides (elements) for attn tiles: b128 fragment reads <=2-way conflicts
#define KSTR 104   /* 64x(96) K tile rows, padded 96->104 */
#define VSTR 72    /* 96x(64) Vt tile rows, padded 64->72 */
#define PSTR 72    /* 16x(64) P tile rows (per wave), padded 64->72 */

// ---------------------------------------------------------------------------
// async global->LDS, 16B per lane. LDS dest wave-uniform base; lane i lands at
// base + i*16.  [m97 pattern]
// ---------------------------------------------------------------------------
__device__ __forceinline__ void gload16(const bf16* gp, bf16* lp) {
    __builtin_amdgcn_global_load_lds(
        (const __attribute__((address_space(1))) unsigned int*)gp,
        (__attribute__((address_space(3))) unsigned int*)lp, 16, 0, 0);
}

// ---------------------------------------------------------------------------
// Transpose + convert: W[R][Cn] (fp32) -> Wt[Cn][R] (bf16)
// ---------------------------------------------------------------------------
__global__ void transpose_kernel(const float* __restrict__ W, bf16* __restrict__ Wt,
                                 int R, int Cn) {
    __shared__ bf16 tile[32][33];
    int tx = threadIdx.x, ty = threadIdx.y;
    int x  = blockIdx.x * 32 + tx;
    int y0 = blockIdx.y * 32;
#pragma unroll
    for (int j = 0; j < 32; j += 8)
        tile[ty + j][tx] = (bf16)W[(size_t)(y0 + ty + j) * Cn + x];
    __syncthreads();
    int y2 = blockIdx.x * 32;
    int x2 = y0 + tx;
#pragma unroll
    for (int j = 0; j < 32; j += 8)
        Wt[(size_t)(y2 + ty + j) * R + x2] = tile[tx][ty + j];
}

// ---------------------------------------------------------------------------
__global__ void sentinel_kernel(float* __restrict__ out, int n) {
    int i = blockIdx.x * 256 + threadIdx.x;
    if (i < n) out[i] = 12345.0f;
}

// ---------------------------------------------------------------------------
__device__ __forceinline__ bf16x8 load8f(const float* p) {
    f32x4 v0 = *(const f32x4*)p;
    f32x4 v1 = *(const f32x4*)(p + 4);
    bf16x8 o;
#pragma unroll
    for (int i = 0; i < 4; ++i) { o[i] = (bf16)v0[i]; o[4 + i] = (bf16)v1[i]; }
    return o;
}

// ---------------------------------------------------------------------------
// GEMM1 fused: qkv[M][2304] = x[M][768] (fp32) @ Wt^T + b; V-range columns
// (n >= 2C) additionally written transposed to Vt[b][c][t] (packed b64).
// A staged via fp32 loads + convert (padded LDS); B staged via global_load_lds.
// ---------------------------------------------------------------------------
__global__ __launch_bounds__(256) void gemm_qkv(const float* __restrict__ A,
                                                const bf16* __restrict__ Bt,
                                                const float* __restrict__ bias,
                                                bf16* __restrict__ Cmat,
                                                bf16* __restrict__ Vt,
                                                int M, int N, int K) {
    __shared__ bf16 lda[128 * 72];
    __shared__ bf16 ldb[128 * 64];
    int tid  = threadIdx.x;
    int w    = tid >> 6;
    int lane = tid & 63;
    int col  = lane & 15, quad = lane >> 4;
    int wr   = w >> 1, wc = w & 1;
    int m0   = blockIdx.y * 128, n0 = blockIdx.x * 128;

    const f32x4 zero = {0.f, 0.f, 0.f, 0.f};
    f32x4 acc[4][4];
#pragma unroll
    for (int mr = 0; mr < 4; ++mr)
#pragma unroll
        for (int nc = 0; nc < 4; ++nc) acc[mr][nc] = zero;

    for (int k0 = 0; k0 < K; k0 += 64) {
#pragma unroll
        for (int i = 0; i < 4; ++i) {
            int chunk = i * 256 + tid;
            int r = chunk >> 3, cc = chunk & 7;
            *(bf16x8*)&lda[r * 72 + cc * 8] = load8f(&A[(size_t)(m0 + r) * K + k0 + cc * 8]);
            int gbase = i * 256 + w * 64;
            int gg = gbase + lane;
            int rb = gg >> 3, cb = gg & 7;
            gload16(&Bt[(size_t)(n0 + rb) * K + k0 + cb * 8], &ldb[gbase * 8]);
        }
        __syncthreads();
#pragma unroll
        for (int ks = 0; ks < 2; ++ks) {
            bf16x8 af[4], bfr[4];
#pragma unroll
            for (int t = 0; t < 4; ++t) {
                af[t]  = *(const bf16x8*)&lda[(wr * 64 + t * 16 + col) * 72 + ks * 32 + quad * 8];
                bfr[t] = *(const bf16x8*)&ldb[(wc * 64 + t * 16 + col) * 64 + ks * 32 + quad * 8];
            }
#pragma unroll
            for (int mr = 0; mr < 4; ++mr)
#pragma unroll
                for (int nc = 0; nc < 4; ++nc)
                    acc[mr][nc] = __builtin_amdgcn_mfma_f32_16x16x32_bf16(
                        af[mr], bfr[nc], acc[mr][nc], 0, 0, 0);
        }
        __syncthreads();
    }

    // qkv store
#pragma unroll
    for (int nc = 0; nc < 4; ++nc) {
        int n = n0 + wc * 64 + nc * 16 + col;
        float bv = bias[n];
#pragma unroll
        for (int mr = 0; mr < 4; ++mr) {
#pragma unroll
            for (int r = 0; r < 4; ++r) {
                int row = m0 + wr * 64 + mr * 16 + quad * 4 + r;
                Cmat[(size_t)row * N + n] = (bf16)(acc[mr][nc][r] + bv);
            }
        }
    }
    // fused Vt write for V-range blocks (n0 >= 2C). 128-row blocks never
    // straddle a batch boundary (T_ = 2048 is a multiple of 128).
    if (n0 >= 2 * C_) {
        int batch = m0 >> 11;
        bf16* Vtb = Vt + (size_t)batch * C_ * T_;
        int t0 = (m0 & 2047) + wr * 64;
#pragma unroll
        for (int nc = 0; nc < 4; ++nc) {
            int n  = n0 + wc * 64 + nc * 16 + col;
            int vc = n - 2 * C_;
            float bv = bias[n];
#pragma unroll
            for (int mr = 0; mr < 4; ++mr) {
                int t = t0 + mr * 16 + quad * 4;
                bf16x4 pk = {(bf16)(acc[mr][nc][0] + bv), (bf16)(acc[mr][nc][1] + bv),
                             (bf16)(acc[mr][nc][2] + bv), (bf16)(acc[mr][nc][3] + bv)};
                *(bf16x4*)&Vtb[(size_t)vc * T_ + t] = pk;
            }
        }
    }
}

// ---------------------------------------------------------------------------
// GEMM2: out[M][768] (fp32) = yb[M][768] (bf16) @ Wt^T + b.  m97-style.
// ---------------------------------------------------------------------------
__global__ __launch_bounds__(256) void gemm_proj(const bf16* __restrict__ A,
                                                 const bf16* __restrict__ Bt,
                                                 const float* __restrict__ bias,
                                                 float* __restrict__ Cmat,
                                                 int M, int N, int K) {
    __shared__ bf16 lda[128 * 64];
    __shared__ bf16 ldb[128 * 64];
    int tid  = threadIdx.x;
    int w    = tid >> 6;
    int lane = tid & 63;
    int col  = lane & 15, quad = lane >> 4;
    int wr   = w >> 1, wc = w & 1;
    int m0   = blockIdx.y * 128, n0 = blockIdx.x * 128;

    const f32x4 zero = {0.f, 0.f, 0.f, 0.f};
    f32x4 acc[4][4];
#pragma unroll
    for (int mr = 0; mr < 4; ++mr)
#pragma unroll
        for (int nc = 0; nc < 4; ++nc) acc[mr][nc] = zero;

    for (int k0 = 0; k0 < K; k0 += 64) {
#pragma unroll
        for (int i = 0; i < 4; ++i) {
            int gbase = i * 256 + w * 64;
            int g  = gbase + lane;
            int r  = g >> 3, cc = g & 7;
            gload16(&A[(size_t)(m0 + r) * K + k0 + cc * 8],  &lda[gbase * 8]);
            gload16(&Bt[(size_t)(n0 + r) * K + k0 + cc * 8], &ldb[gbase * 8]);
        }
        __syncthreads();
#pragma unroll
        for (int ks = 0; ks < 2; ++ks) {
            bf16x8 af[4], bfr[4];
#pragma unroll
            for (int t = 0; t < 4; ++t) {
                af[t]  = *(const bf16x8*)&lda[(wr * 64 + t * 16 + col) * 64 + ks * 32 + quad * 8];
                bfr[t] = *(const bf16x8*)&ldb[(wc * 64 + t * 16 + col) * 64 + ks * 32 + quad * 8];
            }
#pragma unroll
            for (int mr = 0; mr < 4; ++mr)
#pragma unroll
                for (int nc = 0; nc < 4; ++nc)
                    acc[mr][nc] = __builtin_amdgcn_mfma_f32_16x16x32_bf16(
                        af[mr], bfr[nc], acc[mr][nc], 0, 0, 0);
        }
        __syncthreads();
    }

#pragma unroll
    for (int nc = 0; nc < 4; ++nc) {
        int n = n0 + wc * 64 + nc * 16 + col;
        float bv = bias[n];
#pragma unroll
        for (int mr = 0; mr < 4; ++mr) {
#pragma unroll
            for (int r = 0; r < 4; ++r) {
                int row = m0 + wr * 64 + mr * 16 + quad * 4 + r;
                Cmat[(size_t)row * N + n] = acc[mr][nc][r] + bv;
            }
        }
    }
}

// ---------------------------------------------------------------------------
// Fused causal flash attention. Static-exponent softmax (exact; M0 cancels),
// transposed O (all per-query state on lane q=col, zero loop shuffles).
// Grid: 32*nGroups blocks (1 qt each), heavy-first -> 4 blocks/CU resident.
// Staging addresses precomputed, pointer-increment per j-step.
// ---------------------------------------------------------------------------
__global__ __launch_bounds__(256) void attn_kernel(const bf16* __restrict__ qkv,
                                                   const bf16* __restrict__ Vt,
                                                   bf16* __restrict__ y,
                                                   int nGroups) {
    __shared__ bf16 ldsK[64 * KSTR];
    __shared__ bf16 ldsV[96 * VSTR];
    __shared__ bf16 ldsP[4 * 16 * PSTR];
    const int bid  = blockIdx.x;
    const int qt   = 31 - bid / nGroups;      // heavy blocks first
    const int g    = bid % nGroups;
    const int h    = g & 7, b = g >> 3;
    const int tid  = threadIdx.x;
    const int w    = tid >> 6, lane = tid & 63;
    const int col  = lane & 15, quad = lane >> 4;
    const float SCALE2 = 0.10206207261596577f * 1.4426950408889634f; // scale*log2e
    const float M0 = 24.0f;                    // static exponent shift (exact)
    const f32x4 zero = {0.f, 0.f, 0.f, 0.f};

    const bf16* qkvb = qkv + (size_t)b * T_ * QKN_;
    const bf16* Vtbh = Vt + (size_t)(b * H_ + h) * HS_ * T_;
    bf16* yb  = y + (size_t)b * T_ * C_;
    bf16* myP = &ldsP[w * 16 * PSTR];

    const int rbase = qt * 64 + w * 16;

    // Q fragments (B-operand layout; contiguous in k)
    bf16x8 qf[3];
#pragma unroll
    for (int c = 0; c < 3; ++c)
        qf[c] = *(const bf16x8*)&qkvb[(size_t)(rbase + col) * QKN_ + h * HS_ + c * 32 + quad * 8];

    // Precompute staging pointers (advance by fixed strides per j-step)
    const bf16* pK[3]; const bf16* pV[3];
    bf16 *dK[3], *dV[3];
#pragma unroll
    for (int i = 0; i < 3; ++i) {
        int chunk = i * 256 + tid;
        int rK = chunk / 12, cK = chunk - rK * 12;
        pK[i] = qkvb + (size_t)rK * QKN_ + C_ + h * HS_ + cK * 8;
        dK[i] = &ldsK[rK * KSTR + cK * 8];
        int rV = chunk >> 3, cV = chunk & 7;
        pV[i] = Vtbh + (size_t)rV * T_ + cV * 8;
        dV[i] = &ldsV[rV * VSTR + cV * 8];
    }

    f32x4 o[6];
#pragma unroll
    for (int n2 = 0; n2 < 6; ++n2) o[n2] = zero;
    float lsum = 0.f;                      // per-lane partial (query i=col)

    const int njt = qt + 1;
    for (int jt = 0; jt < njt; ++jt) {
        int jb = jt * 64;
        __syncthreads();   // all waves done reading previous K/V
#pragma unroll
        for (int i = 0; i < 3; ++i) {
            *(bf16x8*)dK[i] = *(const bf16x8*)pK[i];
            *(bf16x8*)dV[i] = *(const bf16x8*)pV[i];
            pK[i] += (size_t)64 * QKN_;
            pV[i] += 64;
        }
        __syncthreads();

        // St = K Q^T: lane holds St[j = jb+nb*16+quad*4+r][i = rbase+col]
        bf16x8 kf[4][3];
#pragma unroll
        for (int nb = 0; nb < 4; ++nb)
#pragma unroll
            for (int c = 0; c < 3; ++c)
                kf[nb][c] = *(const bf16x8*)&ldsK[(nb * 16 + col) * KSTR + c * 32 + quad * 8];

        f32x4 st[4];
#pragma unroll
        for (int nb = 0; nb < 4; ++nb) st[nb] = zero;
#pragma unroll
        for (int c = 0; c < 3; ++c)
#pragma unroll
            for (int nb = 0; nb < 4; ++nb)
                st[nb] = __builtin_amdgcn_mfma_f32_16x16x32_bf16(
                    kf[nb][c], qf[c], st[nb], 0, 0, 0);

        // scale to exp2 domain, subtract static M0; mask diagonal tile
        if (jt == njt - 1) {
#pragma unroll
            for (int nb = 0; nb < 4; ++nb)
#pragma unroll
                for (int r = 0; r < 4; ++r) {
                    int jg = jb + nb * 16 + quad * 4 + r;
                    st[nb][r] = (jg <= rbase + col) ? fmaf(st[nb][r], SCALE2, -M0)
                                                    : NEG_BIG;
                }
        } else {
#pragma unroll
            for (int nb = 0; nb < 4; ++nb)
#pragma unroll
                for (int r = 0; r < 4; ++r)
                    st[nb][r] = fmaf(st[nb][r], SCALE2, -M0);
        }

        // p = exp2(st), per-lane partial sum; P -> per-wave LDS (b64)
#pragma unroll
        for (int nb = 0; nb < 4; ++nb) {
#pragma unroll
            for (int r = 0; r < 4; ++r) {
                float pv = exp2f(st[nb][r]);
                st[nb][r] = pv;
                lsum += pv;
            }
            bf16x4 pk = {(bf16)st[nb][0], (bf16)st[nb][1],
                         (bf16)st[nb][2], (bf16)st[nb][3]};
            *(bf16x4*)&myP[col * PSTR + nb * 16 + quad * 4] = pk;
        }

        // Ot += V^T P^T  (A = Vt frag, B = P^T frag)
        bf16x8 vf[6][2];
#pragma unroll
        for (int n2 = 0; n2 < 6; ++n2)
#pragma unroll
            for (int c = 0; c < 2; ++c)
                vf[n2][c] = *(const bf16x8*)&ldsV[(n2 * 16 + col) * VSTR + c * 32 + quad * 8];
        bf16x8 pa0 = *(const bf16x8*)&myP[col * PSTR + quad * 8];
        bf16x8 pa1 = *(const bf16x8*)&myP[col * PSTR + 32 + quad * 8];
#pragma unroll
        for (int n2 = 0; n2 < 6; ++n2)
            o[n2] = __builtin_amdgcn_mfma_f32_16x16x32_bf16(vf[n2][0], pa0, o[n2], 0, 0, 0);
#pragma unroll
        for (int n2 = 0; n2 < 6; ++n2)
            o[n2] = __builtin_amdgcn_mfma_f32_16x16x32_bf16(vf[n2][1], pa1, o[n2], 0, 0, 0);
    }

    // Epilogue: reduce l across the 4 quad-groups, normalize, store y.
    lsum += __shfl_xor(lsum, 16, 64);
    lsum += __shfl_xor(lsum, 32, 64);
    float linv = 1.0f / lsum;
    // lane holds Ot[hs = n2*16 + quad*4 + r][q = rbase + col]
#pragma unroll
    for (int n2 = 0; n2 < 6; ++n2) {
        bf16x4 pk = {(bf16)(o[n2][0] * linv), (bf16)(o[n2][1] * linv),
                     (bf16)(o[n2][2] * linv), (bf16)(o[n2][3] * linv)};
        *(bf16x4*)&yb[(size_t)(rbase + col) * C_ + h * HS_ + n2 * 16 + quad * 4] = pk;
    }
}

// ---------------------------------------------------------------------------
extern "C" void kernel_launch(void* const* d_in, const int* in_sizes, int n_in,
                              void* d_out, int out_size, void* d_ws, size_t ws_size,
                              hipStream_t stream) {
    (void)in_sizes; (void)n_in;
    const float* x      = (const float*)d_in[0];
    const float* W_attn = (const float*)d_in[1];
    const float* b_attn = (const float*)d_in[2];
    const float* W_proj = (const float*)d_in[3];
    const float* b_proj = (const float*)d_in[4];
    float* out = (float*)d_out;

    size_t e_wta = (size_t)QKN_ * C_;
    size_t e_wtp = (size_t)C_ * C_;
    // Path A (batched): Wt | qkv[8192][2304] | Vt[4][768][2048] | yb[8192][768]
    size_t a_qkv = e_wta + e_wtp;
    size_t a_vt  = a_qkv + (size_t)M_ * QKN_;
    size_t a_yb  = a_vt + (size_t)M_ * C_;
    size_t needA = (a_yb + (size_t)M_ * C_) * sizeof(bf16);   // 67.6 MB
    // Path B (per-batch)
    size_t b_qkv = e_wta + e_wtp;
    size_t b_vt  = b_qkv + (size_t)T_ * QKN_;
    size_t b_yb  = b_vt + (size_t)T_ * C_;
    size_t needB = (b_yb + (size_t)T_ * C_) * sizeof(bf16);   // 20.4 MB

    if (ws_size >= needA) {
        bf16* Wt_attn = (bf16*)d_ws;
        bf16* Wt_proj = (bf16*)d_ws + e_wta;
        bf16* qkv     = (bf16*)d_ws + a_qkv;
        bf16* Vt      = (bf16*)d_ws + a_vt;
        bf16* yb      = (bf16*)d_ws + a_yb;
        transpose_kernel<<<dim3(QKN_ / 32, C_ / 32), dim3(32, 8), 0, stream>>>(W_attn, Wt_attn, C_, QKN_);
        transpose_kernel<<<dim3(C_ / 32, C_ / 32), dim3(32, 8), 0, stream>>>(W_proj, Wt_proj, C_, C_);
        gemm_qkv<<<dim3(QKN_ / 128, M_ / 128), 256, 0, stream>>>(
            x, Wt_attn, b_attn, qkv, Vt, M_, QKN_, C_);
        attn_kernel<<<dim3(32 * H_ * B_), 256, 0, stream>>>(qkv, Vt, yb, H_ * B_);
        gemm_proj<<<dim3(C_ / 128, M_ / 128), 256, 0, stream>>>(
            yb, Wt_proj, b_proj, out, M_, C_, C_);
    } else if (ws_size >= needB) {
        bf16* Wt_attn = (bf16*)d_ws;
        bf16* Wt_proj = (bf16*)d_ws + e_wta;
        bf16* qkv     = (bf16*)d_ws + b_qkv;
        bf16* Vt      = (bf16*)d_ws + b_vt;
        bf16* yb      = (bf16*)d_ws + b_yb;
        transpose_kernel<<<dim3(QKN_ / 32, C_ / 32), dim3(32, 8), 0, stream>>>(W_attn, Wt_attn, C_, QKN_);
        transpose_kernel<<<dim3(C_ / 32, C_ / 32), dim3(32, 8), 0, stream>>>(W_proj, Wt_proj, C_, C_);
        for (int b = 0; b < B_; ++b) {
            const float* xb = x + (size_t)b * T_ * C_;
            float* outb     = out + (size_t)b * T_ * C_;
            gemm_qkv<<<dim3(QKN_ / 128, T_ / 128), 256, 0, stream>>>(
                xb, Wt_attn, b_attn, qkv, Vt, T_, QKN_, C_);
            attn_kernel<<<dim3(32 * H_), 256, 0, stream>>>(qkv, Vt, yb, H_);
            gemm_proj<<<dim3(C_ / 128, T_ / 128), 256, 0, stream>>>(
                yb, Wt_proj, b_proj, outb, T_, C_, C_);
        }
    } else {
        sentinel_kernel<<<(out_size + 255) / 256, 256, 0, stream>>>(out, out_size);
    }
}

// Round 10
// 218.548 us; speedup vs baseline: 5.0633x; 1.0721x over previous
//
#include <hip/hip_runtime.h>

typedef __bf16 bf16;
typedef __attribute__((ext_vector_type(4))) __bf16 bf16x4;
typedef __attribute__((ext_vector_type(8))) __bf16 bf16x8;
typedef __attribute__((ext_vector_type(4))) float f32x4;

#define B_   4
#define T_   2048
#define C_   768
#define H_   8
#define HS_  96
#define M_   (B_ * T_)      /* 8192 */
#define QKN_ (3 * C_)       /* 2304 */

#define NEG_BIG (-1e30f)

// LDS strides (elements) for attn tiles: b128 fragment reads <=2-way conflicts
#define KSTR 104   /* 64x(96) K tile rows, padded 96->104 */
#define VSTR 72    /* 96x(64) Vt tile rows, padded 64->72 */
#define PSTR 72    /* 16x(64) P tile rows (per wave), padded 64->72 */

// ---------------------------------------------------------------------------
// Transpose + convert: W[R][Cn] (fp32) -> Wt[Cn][R] (bf16)
// ---------------------------------------------------------------------------
__global__ void transpose_kernel(const float* __restrict__ W, bf16* __restrict__ Wt,
                                 int R, int Cn) {
    __shared__ bf16 tile[32][33];
    int tx = threadIdx.x, ty = threadIdx.y;
    int x  = blockIdx.x * 32 + tx;
    int y0 = blockIdx.y * 32;
#pragma unroll
    for (int j = 0; j < 32; j += 8)
        tile[ty + j][tx] = (bf16)W[(size_t)(y0 + ty + j) * Cn + x];
    __syncthreads();
    int y2 = blockIdx.x * 32;
    int x2 = y0 + tx;
#pragma unroll
    for (int j = 0; j < 32; j += 8)
        Wt[(size_t)(y2 + ty + j) * R + x2] = tile[tx][ty + j];
}

// ---------------------------------------------------------------------------
__global__ void sentinel_kernel(float* __restrict__ out, int n) {
    int i = blockIdx.x * 256 + threadIdx.x;
    if (i < n) out[i] = 12345.0f;
}

__device__ __forceinline__ bf16x8 cvt8(f32x4 v0, f32x4 v1) {
    bf16x8 o;
#pragma unroll
    for (int i = 0; i < 4; ++i) { o[i] = (bf16)v0[i]; o[4 + i] = (bf16)v1[i]; }
    return o;
}

// ---------------------------------------------------------------------------
// GEMM1 fused + PIPELINED: qkv[M][2304] = x[M][768](fp32) @ Wt^T + b.
// V-range columns (n >= 2C) also written transposed to Vt[b][c][t].
// Register-prefetch pipeline: stage k from regs -> barrier -> prefetch k+1
// into regs -> MFMA (hides global latency) -> barrier.
// ---------------------------------------------------------------------------
__global__ __launch_bounds__(256) void gemm_qkv(const float* __restrict__ A,
                                                const bf16* __restrict__ Bt,
                                                const float* __restrict__ bias,
                                                bf16* __restrict__ Cmat,
                                                bf16* __restrict__ Vt,
                                                int M, int N, int K) {
    __shared__ bf16 lda[128 * 72];
    __shared__ bf16 ldb[128 * 72];
    int tid  = threadIdx.x;
    int w    = tid >> 6;
    int lane = tid & 63;
    int col  = lane & 15, quad = lane >> 4;
    int wr   = w >> 1, wc = w & 1;
    int m0   = blockIdx.y * 128, n0 = blockIdx.x * 128;

    // per-thread staging coordinates (4 chunks of 8 elements)
    int rr[4], cc8[4];
#pragma unroll
    for (int i = 0; i < 4; ++i) {
        int chunk = i * 256 + tid;
        rr[i] = chunk >> 3; cc8[i] = (chunk & 7) * 8;
    }

    const f32x4 zero = {0.f, 0.f, 0.f, 0.f};
    f32x4 acc[4][4];
#pragma unroll
    for (int mr = 0; mr < 4; ++mr)
#pragma unroll
        for (int nc = 0; nc < 4; ++nc) acc[mr][nc] = zero;

    // prologue prefetch (k0 = 0)
    f32x4 a0[4], a1[4]; bf16x8 breg[4];
#pragma unroll
    for (int i = 0; i < 4; ++i) {
        const float* ap = &A[(size_t)(m0 + rr[i]) * K + cc8[i]];
        a0[i] = *(const f32x4*)ap;
        a1[i] = *(const f32x4*)(ap + 4);
        breg[i] = *(const bf16x8*)&Bt[(size_t)(n0 + rr[i]) * K + cc8[i]];
    }

    for (int k0 = 0; k0 < K; k0 += 64) {
        // stage current tile from registers (LDS free here)
#pragma unroll
        for (int i = 0; i < 4; ++i) {
            *(bf16x8*)&lda[rr[i] * 72 + cc8[i]] = cvt8(a0[i], a1[i]);
            *(bf16x8*)&ldb[rr[i] * 72 + cc8[i]] = breg[i];
        }
        __syncthreads();
        // prefetch next tile into registers (latency hidden by MFMA below)
        if (k0 + 64 < K) {
            int k1 = k0 + 64;
#pragma unroll
            for (int i = 0; i < 4; ++i) {
                const float* ap = &A[(size_t)(m0 + rr[i]) * K + k1 + cc8[i]];
                a0[i] = *(const f32x4*)ap;
                a1[i] = *(const f32x4*)(ap + 4);
                breg[i] = *(const bf16x8*)&Bt[(size_t)(n0 + rr[i]) * K + k1 + cc8[i]];
            }
        }
#pragma unroll
        for (int ks = 0; ks < 2; ++ks) {
            bf16x8 af[4], bfr[4];
#pragma unroll
            for (int t = 0; t < 4; ++t) {
                af[t]  = *(const bf16x8*)&lda[(wr * 64 + t * 16 + col) * 72 + ks * 32 + quad * 8];
                bfr[t] = *(const bf16x8*)&ldb[(wc * 64 + t * 16 + col) * 72 + ks * 32 + quad * 8];
            }
#pragma unroll
            for (int mr = 0; mr < 4; ++mr)
#pragma unroll
                for (int nc = 0; nc < 4; ++nc)
                    acc[mr][nc] = __builtin_amdgcn_mfma_f32_16x16x32_bf16(
                        af[mr], bfr[nc], acc[mr][nc], 0, 0, 0);
        }
        __syncthreads();
    }

    // qkv store
#pragma unroll
    for (int nc = 0; nc < 4; ++nc) {
        int n = n0 + wc * 64 + nc * 16 + col;
        float bv = bias[n];
#pragma unroll
        for (int mr = 0; mr < 4; ++mr) {
#pragma unroll
            for (int r = 0; r < 4; ++r) {
                int row = m0 + wr * 64 + mr * 16 + quad * 4 + r;
                Cmat[(size_t)row * N + n] = (bf16)(acc[mr][nc][r] + bv);
            }
        }
    }
    // fused Vt write for V-range blocks (n0 >= 2C); 128-row blocks never
    // straddle a batch boundary.
    if (n0 >= 2 * C_) {
        int batch = m0 >> 11;
        bf16* Vtb = Vt + (size_t)batch * C_ * T_;
        int t0 = (m0 & 2047) + wr * 64;
#pragma unroll
        for (int nc = 0; nc < 4; ++nc) {
            int n  = n0 + wc * 64 + nc * 16 + col;
            int vc = n - 2 * C_;
            float bv = bias[n];
#pragma unroll
            for (int mr = 0; mr < 4; ++mr) {
                int t = t0 + mr * 16 + quad * 4;
                bf16x4 pk = {(bf16)(acc[mr][nc][0] + bv), (bf16)(acc[mr][nc][1] + bv),
                             (bf16)(acc[mr][nc][2] + bv), (bf16)(acc[mr][nc][3] + bv)};
                *(bf16x4*)&Vtb[(size_t)vc * T_ + t] = pk;
            }
        }
    }
}

// ---------------------------------------------------------------------------
// GEMM2 PIPELINED: out[M][768](fp32) = yb[M][768](bf16) @ Wt^T + b.
// ---------------------------------------------------------------------------
__global__ __launch_bounds__(256) void gemm_proj(const bf16* __restrict__ A,
                                                 const bf16* __restrict__ Bt,
                                                 const float* __restrict__ bias,
                                                 float* __restrict__ Cmat,
                                                 int M, int N, int K) {
    __shared__ bf16 lda[128 * 72];
    __shared__ bf16 ldb[128 * 72];
    int tid  = threadIdx.x;
    int w    = tid >> 6;
    int lane = tid & 63;
    int col  = lane & 15, quad = lane >> 4;
    int wr   = w >> 1, wc = w & 1;
    int m0   = blockIdx.y * 128, n0 = blockIdx.x * 128;

    int rr[4], cc8[4];
#pragma unroll
    for (int i = 0; i < 4; ++i) {
        int chunk = i * 256 + tid;
        rr[i] = chunk >> 3; cc8[i] = (chunk & 7) * 8;
    }

    const f32x4 zero = {0.f, 0.f, 0.f, 0.f};
    f32x4 acc[4][4];
#pragma unroll
    for (int mr = 0; mr < 4; ++mr)
#pragma unroll
        for (int nc = 0; nc < 4; ++nc) acc[mr][nc] = zero;

    bf16x8 areg[4], breg[4];
#pragma unroll
    for (int i = 0; i < 4; ++i) {
        areg[i] = *(const bf16x8*)&A[(size_t)(m0 + rr[i]) * K + cc8[i]];
        breg[i] = *(const bf16x8*)&Bt[(size_t)(n0 + rr[i]) * K + cc8[i]];
    }

    for (int k0 = 0; k0 < K; k0 += 64) {
#pragma unroll
        for (int i = 0; i < 4; ++i) {
            *(bf16x8*)&lda[rr[i] * 72 + cc8[i]] = areg[i];
            *(bf16x8*)&ldb[rr[i] * 72 + cc8[i]] = breg[i];
        }
        __syncthreads();
        if (k0 + 64 < K) {
            int k1 = k0 + 64;
#pragma unroll
            for (int i = 0; i < 4; ++i) {
                areg[i] = *(const bf16x8*)&A[(size_t)(m0 + rr[i]) * K + k1 + cc8[i]];
                breg[i] = *(const bf16x8*)&Bt[(size_t)(n0 + rr[i]) * K + k1 + cc8[i]];
            }
        }
#pragma unroll
        for (int ks = 0; ks < 2; ++ks) {
            bf16x8 af[4], bfr[4];
#pragma unroll
            for (int t = 0; t < 4; ++t) {
                af[t]  = *(const bf16x8*)&lda[(wr * 64 + t * 16 + col) * 72 + ks * 32 + quad * 8];
                bfr[t] = *(const bf16x8*)&ldb[(wc * 64 + t * 16 + col) * 72 + ks * 32 + quad * 8];
            }
#pragma unroll
            for (int mr = 0; mr < 4; ++mr)
#pragma unroll
                for (int nc = 0; nc < 4; ++nc)
                    acc[mr][nc] = __builtin_amdgcn_mfma_f32_16x16x32_bf16(
                        af[mr], bfr[nc], acc[mr][nc], 0, 0, 0);
        }
        __syncthreads();
    }

#pragma unroll
    for (int nc = 0; nc < 4; ++nc) {
        int n = n0 + wc * 64 + nc * 16 + col;
        float bv = bias[n];
#pragma unroll
        for (int mr = 0; mr < 4; ++mr) {
#pragma unroll
            for (int r = 0; r < 4; ++r) {
                int row = m0 + wr * 64 + mr * 16 + quad * 4 + r;
                Cmat[(size_t)row * N + n] = acc[mr][nc][r] + bv;
            }
        }
    }
}

// ---------------------------------------------------------------------------
// Fused causal flash attention (unchanged from round 9). Static-exponent
// softmax (exact; M0 cancels), transposed O, heavy-first 1-qt blocks.
// ---------------------------------------------------------------------------
__global__ __launch_bounds__(256) void attn_kernel(const bf16* __restrict__ qkv,
                                                   const bf16* __restrict__ Vt,
                                                   bf16* __restrict__ y,
                                                   int nGroups) {
    __shared__ bf16 ldsK[64 * KSTR];
    __shared__ bf16 ldsV[96 * VSTR];
    __shared__ bf16 ldsP[4 * 16 * PSTR];
    const int bid  = blockIdx.x;
    const int qt   = 31 - bid / nGroups;      // heavy blocks first
    const int g    = bid % nGroups;
    const int h    = g & 7, b = g >> 3;
    const int tid  = threadIdx.x;
    const int w    = tid >> 6, lane = tid & 63;
    const int col  = lane & 15, quad = lane >> 4;
    const float SCALE2 = 0.10206207261596577f * 1.4426950408889634f; // scale*log2e
    const float M0 = 24.0f;                    // static exponent shift (exact)
    const f32x4 zero = {0.f, 0.f, 0.f, 0.f};

    const bf16* qkvb = qkv + (size_t)b * T_ * QKN_;
    const bf16* Vtbh = Vt + (size_t)(b * H_ + h) * HS_ * T_;
    bf16* yb  = y + (size_t)b * T_ * C_;
    bf16* myP = &ldsP[w * 16 * PSTR];

    const int rbase = qt * 64 + w * 16;

    bf16x8 qf[3];
#pragma unroll
    for (int c = 0; c < 3; ++c)
        qf[c] = *(const bf16x8*)&qkvb[(size_t)(rbase + col) * QKN_ + h * HS_ + c * 32 + quad * 8];

    const bf16* pK[3]; const bf16* pV[3];
    bf16 *dK[3], *dV[3];
#pragma unroll
    for (int i = 0; i < 3; ++i) {
        int chunk = i * 256 + tid;
        int rK = chunk / 12, cK = chunk - rK * 12;
        pK[i] = qkvb + (size_t)rK * QKN_ + C_ + h * HS_ + cK * 8;
        dK[i] = &ldsK[rK * KSTR + cK * 8];
        int rV = chunk >> 3, cV = chunk & 7;
        pV[i] = Vtbh + (size_t)rV * T_ + cV * 8;
        dV[i] = &ldsV[rV * VSTR + cV * 8];
    }

    f32x4 o[6];
#pragma unroll
    for (int n2 = 0; n2 < 6; ++n2) o[n2] = zero;
    float lsum = 0.f;

    const int njt = qt + 1;
    for (int jt = 0; jt < njt; ++jt) {
        int jb = jt * 64;
        __syncthreads();
#pragma unroll
        for (int i = 0; i < 3; ++i) {
            *(bf16x8*)dK[i] = *(const bf16x8*)pK[i];
            *(bf16x8*)dV[i] = *(const bf16x8*)pV[i];
            pK[i] += (size_t)64 * QKN_;
            pV[i] += 64;
        }
        __syncthreads();

        bf16x8 kf[4][3];
#pragma unroll
        for (int nb = 0; nb < 4; ++nb)
#pragma unroll
            for (int c = 0; c < 3; ++c)
                kf[nb][c] = *(const bf16x8*)&ldsK[(nb * 16 + col) * KSTR + c * 32 + quad * 8];

        f32x4 st[4];
#pragma unroll
        for (int nb = 0; nb < 4; ++nb) st[nb] = zero;
#pragma unroll
        for (int c = 0; c < 3; ++c)
#pragma unroll
            for (int nb = 0; nb < 4; ++nb)
                st[nb] = __builtin_amdgcn_mfma_f32_16x16x32_bf16(
                    kf[nb][c], qf[c], st[nb], 0, 0, 0);

        if (jt == njt - 1) {
#pragma unroll
            for (int nb = 0; nb < 4; ++nb)
#pragma unroll
                for (int r = 0; r < 4; ++r) {
                    int jg = jb + nb * 16 + quad * 4 + r;
                    st[nb][r] = (jg <= rbase + col) ? fmaf(st[nb][r], SCALE2, -M0)
                                                    : NEG_BIG;
                }
        } else {
#pragma unroll
            for (int nb = 0; nb < 4; ++nb)
#pragma unroll
                for (int r = 0; r < 4; ++r)
                    st[nb][r] = fmaf(st[nb][r], SCALE2, -M0);
        }

#pragma unroll
        for (int nb = 0; nb < 4; ++nb) {
#pragma unroll
            for (int r = 0; r < 4; ++r) {
                float pv = exp2f(st[nb][r]);
                st[nb][r] = pv;
                lsum += pv;
            }
            bf16x4 pk = {(bf16)st[nb][0], (bf16)st[nb][1],
                         (bf16)st[nb][2], (bf16)st[nb][3]};
            *(bf16x4*)&myP[col * PSTR + nb * 16 + quad * 4] = pk;
        }

        bf16x8 vf[6][2];
#pragma unroll
        for (int n2 = 0; n2 < 6; ++n2)
#pragma unroll
            for (int c = 0; c < 2; ++c)
                vf[n2][c] = *(const bf16x8*)&ldsV[(n2 * 16 + col) * VSTR + c * 32 + quad * 8];
        bf16x8 pa0 = *(const bf16x8*)&myP[col * PSTR + quad * 8];
        bf16x8 pa1 = *(const bf16x8*)&myP[col * PSTR + 32 + quad * 8];
#pragma unroll
        for (int n2 = 0; n2 < 6; ++n2)
            o[n2] = __builtin_amdgcn_mfma_f32_16x16x32_bf16(vf[n2][0], pa0, o[n2], 0, 0, 0);
#pragma unroll
        for (int n2 = 0; n2 < 6; ++n2)
            o[n2] = __builtin_amdgcn_mfma_f32_16x16x32_bf16(vf[n2][1], pa1, o[n2], 0, 0, 0);
    }

    lsum += __shfl_xor(lsum, 16, 64);
    lsum += __shfl_xor(lsum, 32, 64);
    float linv = 1.0f / lsum;
#pragma unroll
    for (int n2 = 0; n2 < 6; ++n2) {
        bf16x4 pk = {(bf16)(o[n2][0] * linv), (bf16)(o[n2][1] * linv),
                     (bf16)(o[n2][2] * linv), (bf16)(o[n2][3] * linv)};
        *(bf16x4*)&yb[(size_t)(rbase + col) * C_ + h * HS_ + n2 * 16 + quad * 4] = pk;
    }
}

// ---------------------------------------------------------------------------
extern "C" void kernel_launch(void* const* d_in, const int* in_sizes, int n_in,
                              void* d_out, int out_size, void* d_ws, size_t ws_size,
                              hipStream_t stream) {
    (void)in_sizes; (void)n_in;
    const float* x      = (const float*)d_in[0];
    const float* W_attn = (const float*)d_in[1];
    const float* b_attn = (const float*)d_in[2];
    const float* W_proj = (const float*)d_in[3];
    const float* b_proj = (const float*)d_in[4];
    float* out = (float*)d_out;

    size_t e_wta = (size_t)QKN_ * C_;
    size_t e_wtp = (size_t)C_ * C_;
    // Path A (batched): Wt | qkv[8192][2304] | Vt[4][768][2048] | yb[8192][768]
    size_t a_qkv = e_wta + e_wtp;
    size_t a_vt  = a_qkv + (size_t)M_ * QKN_;
    size_t a_yb  = a_vt + (size_t)M_ * C_;
    size_t needA = (a_yb + (size_t)M_ * C_) * sizeof(bf16);   // 67.6 MB
    // Path B (per-batch)
    size_t b_qkv = e_wta + e_wtp;
    size_t b_vt  = b_qkv + (size_t)T_ * QKN_;
    size_t b_yb  = b_vt + (size_t)T_ * C_;
    size_t needB = (b_yb + (size_t)T_ * C_) * sizeof(bf16);   // 20.4 MB

    if (ws_size >= needA) {
        bf16* Wt_attn = (bf16*)d_ws;
        bf16* Wt_proj = (bf16*)d_ws + e_wta;
        bf16* qkv     = (bf16*)d_ws + a_qkv;
        bf16* Vt      = (bf16*)d_ws + a_vt;
        bf16* yb      = (bf16*)d_ws + a_yb;
        transpose_kernel<<<dim3(QKN_ / 32, C_ / 32), dim3(32, 8), 0, stream>>>(W_attn, Wt_attn, C_, QKN_);
        transpose_kernel<<<dim3(C_ / 32, C_ / 32), dim3(32, 8), 0, stream>>>(W_proj, Wt_proj, C_, C_);
        gemm_qkv<<<dim3(QKN_ / 128, M_ / 128), 256, 0, stream>>>(
            x, Wt_attn, b_attn, qkv, Vt, M_, QKN_, C_);
        attn_kernel<<<dim3(32 * H_ * B_), 256, 0, stream>>>(qkv, Vt, yb, H_ * B_);
        gemm_proj<<<dim3(C_ / 128, M_ / 128), 256, 0, stream>>>(
            yb, Wt_proj, b_proj, out, M_, C_, C_);
    } else if (ws_size >= needB) {
        bf16* Wt_attn = (bf16*)d_ws;
        bf16* Wt_proj = (bf16*)d_ws + e_wta;
        bf16* qkv     = (bf16*)d_ws + b_qkv;
        bf16* Vt      = (bf16*)d_ws + b_vt;
        bf16* yb      = (bf16*)d_ws + b_yb;
        transpose_kernel<<<dim3(QKN_ / 32, C_ / 32), dim3(32, 8), 0, stream>>>(W_attn, Wt_attn, C_, QKN_);
        transpose_kernel<<<dim3(C_ / 32, C_ / 32), dim3(32, 8), 0, stream>>>(W_proj, Wt_proj, C_, C_);
        for (int b = 0; b < B_; ++b) {
            const float* xb = x + (size_t)b * T_ * C_;
            float* outb     = out + (size_t)b * T_ * C_;
            gemm_qkv<<<dim3(QKN_ / 128, T_ / 128), 256, 0, stream>>>(
                xb, Wt_attn, b_attn, qkv, Vt, T_, QKN_, C_);
            attn_kernel<<<dim3(32 * H_), 256, 0, stream>>>(qkv, Vt, yb, H_);
            gemm_proj<<<dim3(C_ / 128, T_ / 128), 256, 0, stream>>>(
                yb, Wt_proj, b_proj, outb, T_, C_, C_);
        }
    } else {
        sentinel_kernel<<<(out_size + 255) / 256, 256, 0, stream>>>(out, out_size);
    }
}